// Round 1
// baseline (657.673 us; speedup 1.0000x reference)
//
#include <hip/hip_runtime.h>
#include <math.h>

#define HWP 16384   // 128*128 pooled plane
#define HPIX 128

// ---------------- workspace layout (float offsets) ----------------
static const size_t PRE_OFF  = 0;          // 4*192*16384 = 12,582,912
static const size_t QKV_OFF  = 12582912;   // 12,582,912
// after dw3x3, PRE region is dead -> reuse:
static const size_t ATTN_OFF = 0;          // 4,194,304
static const size_t OUT3_OFF = 4194304;    // 4,194,304
static const size_t COVP_OFF = 8388608;    // 4*128*4096 = 2,097,152
static const size_t MEAN_OFF = 10485760;   // 256
static const size_t IDX_OFF  = 10486016;   // 256 ints
static const size_t INV_OFF  = 10486272;   // 256 ints
static const size_t GT_OFF   = 10486528;   // 4096
static const size_t DT_OFF   = 10490624;   // 2048
static const size_t UT_OFF   = 10492672;   // 2048
static const size_t PT_OFF   = 10494720;   // 4096

// ---------------- 1: maxpool2 + conv1x1 (x -> qkv_pre) ----------------
__global__ __launch_bounds__(256) void k_pool_conv(
    const float* __restrict__ x, const float* __restrict__ qkv_w,
    float* __restrict__ pre) {
  int b = blockIdx.x >> 8;          // 256 tiles / batch
  int pix0 = (blockIdx.x & 255) * 64;
  __shared__ float xt[64 * 64];     // [c][p]
  int t = threadIdx.x;
  for (int i = 0; i < 16; ++i) {
    int f = i * 256 + t;
    int c = f >> 6, p = f & 63;
    int pix = pix0 + p;
    int y = pix >> 7, xx = pix & 127;
    const float* src = x + ((size_t)(b * 64 + c) * 65536) + (2 * y) * 256 + 2 * xx;
    float v0 = src[0], v1 = src[1], v2 = src[256], v3 = src[257];
    xt[c * 64 + p] = fmaxf(fmaxf(v0, v1), fmaxf(v2, v3));
  }
  __syncthreads();
  int p = t & 63;
  int orow = t >> 6;                 // wave-uniform
  for (int j = 0; j < 48; j += 8) {
    float acc[8] = {0.f, 0.f, 0.f, 0.f, 0.f, 0.f, 0.f, 0.f};
    for (int c = 0; c < 64; ++c) {
      float xv = xt[c * 64 + p];
#pragma unroll
      for (int u = 0; u < 8; ++u) {
        int o = orow + 4 * (j + u);
        acc[u] = fmaf(qkv_w[o * 64 + c], xv, acc[u]);
      }
    }
#pragma unroll
    for (int u = 0; u < 8; ++u) {
      int o = orow + 4 * (j + u);
      pre[((size_t)b * 192 + o) * HWP + pix0 + p] = acc[u];
    }
  }
}

// ---------------- 2: depthwise 3x3, zero pad (pre -> qkv) ----------------
__global__ __launch_bounds__(256) void k_dw3x3_zero(
    const float* __restrict__ pre, const float* __restrict__ lce_w,
    float* __restrict__ qkv) {
  int gid = blockIdx.x * 256 + threadIdx.x;   // 4*192*16384 total
  int pix = gid & (HWP - 1);
  int bc = gid >> 14;
  int ch = bc % 192;
  int y = pix >> 7, xx = pix & 127;
  const float* w = lce_w + ch * 9;
  const float* base = pre + (size_t)bc * HWP;
  float acc = 0.f;
#pragma unroll
  for (int dy = -1; dy <= 1; ++dy) {
    int yy = y + dy;
    if (yy < 0 || yy > 127) continue;
#pragma unroll
    for (int dx = -1; dx <= 1; ++dx) {
      int xc = xx + dx;
      if (xc < 0 || xc > 127) continue;
      acc = fmaf(w[(dy + 1) * 3 + dx + 1], base[yy * 128 + xc], acc);
    }
  }
  qkv[gid] = acc;
}

// ---------------- 3a: per-channel mean of q ----------------
__global__ __launch_bounds__(256) void k_mean(
    const float* __restrict__ qkv, float* __restrict__ mean) {
  int bc = blockIdx.x;              // b*64 + c
  int b = bc >> 6, c = bc & 63;
  const float* src = qkv + ((size_t)b * 192 + c) * HWP;
  float s = 0.f;
  for (int i = threadIdx.x; i < HWP; i += 256) s += src[i];
  __shared__ float red[4];
  for (int off = 32; off > 0; off >>= 1) s += __shfl_down(s, off);
  int t = threadIdx.x;
  if ((t & 63) == 0) red[t >> 6] = s;
  __syncthreads();
  if (t == 0) mean[bc] = (red[0] + red[1] + red[2] + red[3]) * (1.f / 16384.f);
}

// ---------------- 3b: centered cov partials (chunks of 128) ----------------
__global__ __launch_bounds__(256) void k_covpart(
    const float* __restrict__ qkv, const float* __restrict__ mean,
    float* __restrict__ covp) {
  int blk = blockIdx.x;             // b*128 + chunk
  int b = blk >> 7, chunk = blk & 127;
  int e0 = chunk * 128;
  __shared__ float qc[64 * 129];    // +1 pad breaks stride conflicts
  int t = threadIdx.x;
  for (int i = 0; i < 32; ++i) {
    int f = i * 256 + t;
    int c = f >> 7, e = f & 127;
    qc[c * 129 + e] = qkv[((size_t)b * 192 + c) * HWP + e0 + e] - mean[b * 64 + c];
  }
  __syncthreads();
  int d = t & 63;
  int crow = t >> 6;                // wave-uniform
  float acc[16];
#pragma unroll
  for (int i = 0; i < 16; ++i) acc[i] = 0.f;
  for (int e = 0; e < 128; ++e) {
    float qd = qc[d * 129 + e];
#pragma unroll
    for (int i = 0; i < 16; ++i) {
      int c = crow + 4 * i;
      acc[i] = fmaf(qc[c * 129 + e], qd, acc[i]);
    }
  }
  float* dst = covp + (size_t)blk * 4096;
#pragma unroll
  for (int i = 0; i < 16; ++i) {
    int c = crow + 4 * i;
    dst[c * 64 + d] = acc[i];       // == dst[i*256 + t], coalesced
  }
}

// ---------------- 3c: reduce cov, correlation-mean sim, stable rank ----------------
__global__ __launch_bounds__(256) void k_simsort(
    const float* __restrict__ covp, int* __restrict__ idx, int* __restrict__ inv) {
  int b = blockIdx.x;               // 4 blocks
  __shared__ float covs[4096];
  __shared__ float stds[64];
  __shared__ float sims[64];
  int t = threadIdx.x;
  for (int i = 0; i < 16; ++i) {
    int pp = i * 256 + t;
    const float* src = covp + (size_t)b * 128 * 4096 + pp;
    float s = 0.f;
    for (int ch = 0; ch < 128; ++ch) s += src[ch * 4096];
    covs[pp] = s;
  }
  __syncthreads();
  if (t < 64) stds[t] = sqrtf(covs[t * 64 + t] + 1e-8f);
  __syncthreads();
  if (t < 64) {
    float s = 0.f;
    float sc = stds[t];
    for (int d2 = 0; d2 < 64; ++d2) {
      float denom = fmaxf(sc * stds[d2], 1e-8f);
      s += covs[d2 * 64 + t] / denom;   // symmetric matrix: bitwise equal to [t][d2]
    }
    sims[t] = s * (1.f / 64.f);
  }
  __syncthreads();
  if (t < 64) {
    float sv = sims[t];
    int r = 0;
    for (int d2 = 0; d2 < 64; ++d2) {
      float o = sims[d2];
      if (o > sv || (o == sv && d2 < t)) r++;
    }
    idx[b * 64 + r] = t;
    inv[b * 64 + t] = r;
  }
}

// ---------------- 6: transpose pointwise weights ----------------
__global__ __launch_bounds__(256) void k_prep(
    const float* __restrict__ gating_w, const float* __restrict__ down_w,
    const float* __restrict__ up_w, const float* __restrict__ proj_w,
    float* __restrict__ gT, float* __restrict__ dT,
    float* __restrict__ uT, float* __restrict__ pT) {
  int t = blockIdx.x * 256 + threadIdx.x;
  if (t < 4096) {
    int o = t >> 6, c2 = t & 63;
    gT[c2 * 64 + o] = gating_w[t];
    pT[c2 * 64 + o] = proj_w[t];
  }
  if (t < 2048) {
    int o = t >> 6, c2 = t & 63;      // down_w (32,64)
    dT[c2 * 32 + o] = down_w[t];
    int o2 = t >> 5, c3 = t & 31;     // up_w (64,32)
    uT[c3 * 64 + o2] = up_w[t];
  }
}

// ---------------- 7: halo block attention + gate, scatter to original channels ----------------
__global__ __launch_bounds__(64) void k_attn(
    const float* __restrict__ qkv, const int* __restrict__ idx,
    const float* __restrict__ gate_w, const float* __restrict__ gate_b,
    const float* __restrict__ temp, const float* __restrict__ rel_h,
    const float* __restrict__ rel_w, float* __restrict__ attn_out) {
  int bi = blockIdx.x;
  int head = bi & 3;
  int wj = (bi >> 2) & 15;
  int hi = (bi >> 6) & 15;
  int b = bi >> 10;
  __shared__ __align__(16) float kr[100 * 20];  // stride 20: 80B rows, 16B aligned
  __shared__ __align__(16) float vr[100 * 20];
  __shared__ float rn[100];
  __shared__ float gw[256];
  __shared__ float gb[16];
  __shared__ int chg[16];
  int t = threadIdx.x;
  if (t < 16) {
    chg[t] = idx[b * 64 + head * 16 + t];
    gb[t] = gate_b[head * 16 + t];
  }
  __syncthreads();
  const size_t bb = (size_t)b * 192 * HWP;
  // K/V halo load, consecutive lanes -> consecutive positions (coalesced rows)
  for (int i = 0; i < 25; ++i) {
    int f = i * 64 + t;               // 1600 = 16ch * 100pos
    int ch = f / 100;
    int pos = f - ch * 100;
    int py = pos / 10, px = pos - py * 10;
    int ky = hi * 8 + py - 1, kx = wj * 8 + px - 1;
    bool ok = (ky >= 0) && (ky < 128) && (kx >= 0) && (kx < 128);
    int sp = ky * 128 + kx;
    float kv = ok ? qkv[bb + (size_t)(64 + chg[ch]) * HWP + sp] : 0.f;
    float vv = ok ? qkv[bb + (size_t)(128 + chg[ch]) * HWP + sp] : 0.f;
    kv += (ch < 8) ? rel_h[(head * 10 + py) * 8 + ch]
                   : rel_w[(head * 10 + px) * 8 + (ch - 8)];
    kr[pos * 20 + ch] = kv;
    vr[pos * 20 + ch] = vv;
  }
  for (int i = 0; i < 4; ++i) {
    int f = i * 64 + t;
    if (f < 256) gw[f] = gate_w[head * 256 + f];
  }
  __syncthreads();
  if (t < 100) {                      // two waves' worth? no: 64 threads; loop twice
    float s = 0.f;
#pragma unroll
    for (int ch = 0; ch < 16; ++ch) { float v = kr[t * 20 + ch]; s += v * v; }
    rn[t] = 1.f / fmaxf(sqrtf(s), 1e-12f);
  }
  { // remaining 36 rows
    int t2 = t + 64;
    if (t2 < 100) {
      float s = 0.f;
#pragma unroll
      for (int ch = 0; ch < 16; ++ch) { float v = kr[t2 * 20 + ch]; s += v * v; }
      rn[t2] = 1.f / fmaxf(sqrtf(s), 1e-12f);
    }
  }
  __syncthreads();
  // per-query
  int qy = hi * 8 + (t >> 3), qx = wj * 8 + (t & 7);
  float q[16];
  float qs = 0.f;
#pragma unroll
  for (int ch = 0; ch < 16; ++ch) {
    q[ch] = qkv[bb + (size_t)chg[ch] * HWP + qy * 128 + qx];
    qs += q[ch] * q[ch];
  }
  float qn = 1.f / fmaxf(sqrtf(qs), 1e-12f);
  float T = expf(temp[head]);
  float out[16];
#pragma unroll
  for (int ch = 0; ch < 16; ++ch) out[ch] = 0.f;
  float wsum = 0.f;
  for (int kk = 0; kk < 100; ++kk) {
    const float4* kp = (const float4*)(kr + kk * 20);
    const float4* vp = (const float4*)(vr + kk * 20);
    float kv[16], vv[16];
    *(float4*)(kv + 0)  = kp[0]; *(float4*)(kv + 4)  = kp[1];
    *(float4*)(kv + 8)  = kp[2]; *(float4*)(kv + 12) = kp[3];
    *(float4*)(vv + 0)  = vp[0]; *(float4*)(vv + 4)  = vp[1];
    *(float4*)(vv + 8)  = vp[2]; *(float4*)(vv + 12) = vp[3];
    float dacc = 0.f;
#pragma unroll
    for (int ch = 0; ch < 16; ++ch) dacc = fmaf(q[ch], kv[ch], dacc);
    float d = dacc * qn * rn[kk] * T;
    float e = expf(d - T);            // shift by upper bound: exact softmax, no max pass
    wsum += e;
#pragma unroll
    for (int ch = 0; ch < 16; ++ch) out[ch] = fmaf(e, vv[ch], out[ch]);
  }
  float winv = 1.f / wsum;
#pragma unroll
  for (int o = 0; o < 16; ++o) {
    float gsv = gb[o];
#pragma unroll
    for (int c = 0; c < 16; ++c) gsv = fmaf(gw[o * 16 + c], q[c], gsv);
    float sig = 1.f / (1.f + expf(-gsv));
    attn_out[((size_t)b * 64 + chg[o]) * HWP + qy * 128 + qx] = out[o] * winv * sig;
  }
}

// ---------------- 8: mixed -> gating -> down -> up -> (+attn) -> proj ----------------
__global__ __launch_bounds__(256) void k_post(
    const float* __restrict__ attn, const float* __restrict__ qkv,
    const float* __restrict__ gT, const float* __restrict__ gating_b,
    const float* __restrict__ dT, const float* __restrict__ down_b,
    const float* __restrict__ uT, const float* __restrict__ up_b,
    const float* __restrict__ pT, float* __restrict__ out3) {
  int bi = blockIdx.x;
  int b = bi >> 10;
  int pix0 = (bi & 1023) << 4;        // 16 pixels / block
  int t = threadIdx.x;
  int c = t & 63;
  int pq = t >> 6;                    // wave id; pixels pq*4 .. pq*4+3
  __shared__ float ats[16 * 65];
  __shared__ float ms[16 * 65];
  __shared__ float gs[16 * 65];
  __shared__ float ts[16 * 33];
  __shared__ float os[16 * 65];
  __shared__ float outs[16 * 65];
  for (int i = 0; i < 4; ++i) {       // coalesced remapped load
    int f = (i << 8) + t;
    int cc = f >> 4, pp = f & 15;
    int g = pix0 + pp;
    float a  = attn[((size_t)b * 64 + cc) * HWP + g];
    float qv = qkv[((size_t)b * 192 + cc) * HWP + g];
    float kv = qkv[((size_t)b * 192 + 64 + cc) * HWP + g];
    ats[pp * 65 + cc] = a;
    ms[pp * 65 + cc] = a + qv + kv;   // mixed = attn_out + (q + k)  (cache un-permutes to q+k)
  }
  __syncthreads();
  { // gating conv + exact gelu, * mixed
    float gbc = gating_b[c];
    float acc[4] = {gbc, gbc, gbc, gbc};
    for (int d2 = 0; d2 < 64; ++d2) {
      float w = gT[d2 * 64 + c];
#pragma unroll
      for (int i = 0; i < 4; ++i)
        acc[i] = fmaf(w, ms[(pq * 4 + i) * 65 + d2], acc[i]);
    }
#pragma unroll
    for (int i = 0; i < 4; ++i) {
      int p = pq * 4 + i;
      float a = acc[i];
      float ge = 0.5f * a * (1.f + erff(a * 0.70710678118654752f));
      gs[p * 65 + c] = ge * ms[p * 65 + c];
    }
  }
  __syncthreads();
  if (c < 32) { // down 64->32
    float dbc = down_b[c];
    float acc[4] = {dbc, dbc, dbc, dbc};
    for (int d2 = 0; d2 < 64; ++d2) {
      float w = dT[d2 * 32 + c];
#pragma unroll
      for (int i = 0; i < 4; ++i)
        acc[i] = fmaf(w, gs[(pq * 4 + i) * 65 + d2], acc[i]);
    }
#pragma unroll
    for (int i = 0; i < 4; ++i) ts[(pq * 4 + i) * 33 + c] = acc[i];
  }
  __syncthreads();
  { // up 32->64, residual add of attn
    float ubc = up_b[c];
    float acc[4] = {ubc, ubc, ubc, ubc};
    for (int d2 = 0; d2 < 32; ++d2) {
      float w = uT[d2 * 64 + c];
#pragma unroll
      for (int i = 0; i < 4; ++i)
        acc[i] = fmaf(w, ts[(pq * 4 + i) * 33 + d2], acc[i]);
    }
#pragma unroll
    for (int i = 0; i < 4; ++i) {
      int p = pq * 4 + i;
      os[p * 65 + c] = ats[p * 65 + c] + acc[i];
    }
  }
  __syncthreads();
  { // proj (no bias)
    float acc[4] = {0.f, 0.f, 0.f, 0.f};
    for (int d2 = 0; d2 < 64; ++d2) {
      float w = pT[d2 * 64 + c];
#pragma unroll
      for (int i = 0; i < 4; ++i)
        acc[i] = fmaf(w, os[(pq * 4 + i) * 65 + d2], acc[i]);
    }
#pragma unroll
    for (int i = 0; i < 4; ++i) outs[(pq * 4 + i) * 65 + c] = acc[i];
  }
  __syncthreads();
  for (int i = 0; i < 4; ++i) {       // coalesced remapped store
    int f = (i << 8) + t;
    int cc = f >> 4, pp = f & 15;
    out3[((size_t)b * 64 + cc) * HWP + pix0 + pp] = outs[pp * 65 + cc];
  }
}

// ---------------- 9: dw3x3 reflect + bias + bilinear x2 (align-corners) ----------------
__global__ __launch_bounds__(256) void k_final(
    const float* __restrict__ out3, const float* __restrict__ lp_w,
    const float* __restrict__ lp_b, float* __restrict__ out) {
  int bi = blockIdx.x;                 // (b*64+ch)*8 + rt
  int rt = bi & 7;
  int bc = bi >> 3;
  int ch = bc & 63;
  int r0 = rt * 16;
  __shared__ float tin[20 * 128];      // input rows r0-2 .. r0+17 (reflected)
  __shared__ float tdw[18 * 128];      // dw rows r0-1 .. r0+16
  int t = threadIdx.x;
  const float* src = out3 + (size_t)bc * HWP;
  for (int i = 0; i < 10; ++i) {
    int f = i * 256 + t;               // 2560 exactly
    int r = f >> 7, xx = f & 127;
    int ry = r0 - 2 + r;
    ry = ry < 0 ? -ry : (ry > 127 ? 254 - ry : ry);
    tin[f] = src[ry * 128 + xx];
  }
  __syncthreads();
  float w0 = lp_w[ch * 9 + 0], w1 = lp_w[ch * 9 + 1], w2 = lp_w[ch * 9 + 2];
  float w3 = lp_w[ch * 9 + 3], w4 = lp_w[ch * 9 + 4], w5 = lp_w[ch * 9 + 5];
  float w6 = lp_w[ch * 9 + 6], w7 = lp_w[ch * 9 + 7], w8 = lp_w[ch * 9 + 8];
  float bias = lp_b[ch];
  for (int i = 0; i < 9; ++i) {
    int f = i * 256 + t;               // 2304 exactly
    int r = f >> 7, xx = f & 127;
    int xm = (xx == 0) ? 1 : xx - 1;
    int xp = (xx == 127) ? 126 : xx + 1;
    const float* r0p = tin + r * 128;
    const float* r1p = r0p + 128;
    const float* r2p = r1p + 128;
    float acc = bias;
    acc = fmaf(w0, r0p[xm], acc); acc = fmaf(w1, r0p[xx], acc); acc = fmaf(w2, r0p[xp], acc);
    acc = fmaf(w3, r1p[xm], acc); acc = fmaf(w4, r1p[xx], acc); acc = fmaf(w5, r1p[xp], acc);
    acc = fmaf(w6, r2p[xm], acc); acc = fmaf(w7, r2p[xx], acc); acc = fmaf(w8, r2p[xp], acc);
    tdw[f] = acc;
  }
  __syncthreads();
  const float s = (float)(127.0 / 255.0);
  float* dst = out + (size_t)bc * 65536;
  for (int i = 0; i < 32; ++i) {
    int f = i * 256 + t;               // 8192 exactly: rows 2r0..2r0+31, cols 0..255
    int vr = f >> 8, vx = f & 255;
    int v = 2 * r0 + vr;
    float cy = (float)v * s;
    int ly = (int)floorf(cy); if (ly > 126) ly = 126;
    float wy = cy - (float)ly;
    float cx = (float)vx * s;
    int lx = (int)floorf(cx); if (lx > 126) lx = 126;
    float wx = cx - (float)lx;
    int lr = ly - r0 + 1;              // tdw row index
    float a  = tdw[lr * 128 + lx];
    float bq = tdw[lr * 128 + lx + 1];
    float c2 = tdw[(lr + 1) * 128 + lx];
    float d2 = tdw[(lr + 1) * 128 + lx + 1];
    float t0 = a  * (1.f - wy) + c2 * wy;   // y-lerp first (matches ref order)
    float t1 = bq * (1.f - wy) + d2 * wy;
    dst[v * 256 + vx] = t0 * (1.f - wx) + t1 * wx;
  }
}

extern "C" void kernel_launch(void* const* d_in, const int* in_sizes, int n_in,
                              void* d_out, int out_size, void* d_ws, size_t ws_size,
                              hipStream_t stream) {
  (void)in_sizes; (void)n_in; (void)out_size; (void)ws_size;
  const float* x        = (const float*)d_in[0];
  const float* qkv_w    = (const float*)d_in[1];
  const float* lce_w    = (const float*)d_in[2];
  const float* gate_w   = (const float*)d_in[3];
  const float* gate_b   = (const float*)d_in[4];
  const float* temp     = (const float*)d_in[5];
  const float* rel_h    = (const float*)d_in[6];
  const float* rel_w    = (const float*)d_in[7];
  const float* down_w   = (const float*)d_in[8];
  const float* down_b   = (const float*)d_in[9];
  const float* up_w     = (const float*)d_in[10];
  const float* up_b     = (const float*)d_in[11];
  const float* gating_w = (const float*)d_in[12];
  const float* gating_b = (const float*)d_in[13];
  const float* proj_w   = (const float*)d_in[14];
  const float* lp_w     = (const float*)d_in[15];
  const float* lp_b     = (const float*)d_in[16];
  float* fws = (float*)d_ws;
  float* outp = (float*)d_out;

  float* pre  = fws + PRE_OFF;
  float* qkv  = fws + QKV_OFF;
  float* attn = fws + ATTN_OFF;
  float* out3 = fws + OUT3_OFF;
  float* covp = fws + COVP_OFF;
  float* mean = fws + MEAN_OFF;
  int* idx = (int*)(fws + IDX_OFF);
  int* inv = (int*)(fws + INV_OFF);
  float* gT = fws + GT_OFF;
  float* dT = fws + DT_OFF;
  float* uT = fws + UT_OFF;
  float* pT = fws + PT_OFF;

  k_pool_conv<<<1024, 256, 0, stream>>>(x, qkv_w, pre);
  k_dw3x3_zero<<<49152, 256, 0, stream>>>(pre, lce_w, qkv);
  k_mean<<<256, 256, 0, stream>>>(qkv, mean);
  k_covpart<<<512, 256, 0, stream>>>(qkv, mean, covp);
  k_simsort<<<4, 256, 0, stream>>>(covp, idx, inv);
  k_prep<<<16, 256, 0, stream>>>(gating_w, down_w, up_w, proj_w, gT, dT, uT, pT);
  k_attn<<<4096, 64, 0, stream>>>(qkv, idx, gate_w, gate_b, temp, rel_h, rel_w, attn);
  k_post<<<4096, 256, 0, stream>>>(attn, qkv, gT, gating_b, dT, down_b, uT, up_b, pT, out3);
  k_final<<<2048, 256, 0, stream>>>(out3, lp_w, lp_b, outp);
  (void)inv;
}

// Round 2
// 557.989 us; speedup vs baseline: 1.1786x; 1.1786x over previous
//
#include <hip/hip_runtime.h>
#include <math.h>

#define HWP 16384   // 128*128 pooled plane

// ---------------- workspace layout (float offsets) ----------------
static const size_t PRE_OFF  = 0;          // 4*192*16384 = 12,582,912
static const size_t QKV_OFF  = 12582912;   // 12,582,912
// after dw3x3, PRE region is dead -> reuse:
static const size_t ATTN_OFF = 0;          // 4,194,304
static const size_t OUT3_OFF = 4194304;    // 4,194,304
static const size_t COVP_OFF = 8388608;    // 4*128*4096 = 2,097,152
static const size_t MEAN_OFF = 10485760;   // 256
static const size_t IDX_OFF  = 10486016;   // 256 ints
static const size_t INV_OFF  = 10486272;   // 256 ints
static const size_t COVS_OFF = 10486528;   // 4*4096 = 16,384

// ---------------- 1: maxpool2 + conv1x1 (x -> qkv_pre) ----------------
__global__ __launch_bounds__(256) void k_pool_conv(
    const float* __restrict__ x, const float* __restrict__ qkv_w,
    float* __restrict__ pre) {
  int b = blockIdx.x >> 8;          // 256 tiles / batch
  int pix0 = (blockIdx.x & 255) * 64;
  __shared__ float xt[64 * 64];     // [c][p]
  int t = threadIdx.x;
  for (int i = 0; i < 16; ++i) {
    int f = i * 256 + t;
    int c = f >> 6, p = f & 63;
    int pix = pix0 + p;
    int y = pix >> 7, xx = pix & 127;
    const float* src = x + ((size_t)(b * 64 + c) * 65536) + (2 * y) * 256 + 2 * xx;
    float v0 = src[0], v1 = src[1], v2 = src[256], v3 = src[257];
    xt[c * 64 + p] = fmaxf(fmaxf(v0, v1), fmaxf(v2, v3));
  }
  __syncthreads();
  int p = t & 63;
  int orow = t >> 6;                 // wave-uniform
  for (int j = 0; j < 48; j += 8) {
    float acc[8] = {0.f, 0.f, 0.f, 0.f, 0.f, 0.f, 0.f, 0.f};
    for (int c = 0; c < 64; ++c) {
      float xv = xt[c * 64 + p];
#pragma unroll
      for (int u = 0; u < 8; ++u) {
        int o = orow + 4 * (j + u);
        acc[u] = fmaf(qkv_w[o * 64 + c], xv, acc[u]);
      }
    }
#pragma unroll
    for (int u = 0; u < 8; ++u) {
      int o = orow + 4 * (j + u);
      pre[((size_t)b * 192 + o) * HWP + pix0 + p] = acc[u];
    }
  }
}

// ---------------- 2: depthwise 3x3, zero pad (pre -> qkv) ----------------
__global__ __launch_bounds__(256) void k_dw3x3_zero(
    const float* __restrict__ pre, const float* __restrict__ lce_w,
    float* __restrict__ qkv) {
  int gid = blockIdx.x * 256 + threadIdx.x;   // 4*192*16384 total
  int pix = gid & (HWP - 1);
  int bc = gid >> 14;
  int ch = bc % 192;
  int y = pix >> 7, xx = pix & 127;
  const float* w = lce_w + ch * 9;
  const float* base = pre + (size_t)bc * HWP;
  float acc = 0.f;
#pragma unroll
  for (int dy = -1; dy <= 1; ++dy) {
    int yy = y + dy;
    if (yy < 0 || yy > 127) continue;
#pragma unroll
    for (int dx = -1; dx <= 1; ++dx) {
      int xc = xx + dx;
      if (xc < 0 || xc > 127) continue;
      acc = fmaf(w[(dy + 1) * 3 + dx + 1], base[yy * 128 + xc], acc);
    }
  }
  qkv[gid] = acc;
}

// ---------------- 3a: per-channel mean of q ----------------
__global__ __launch_bounds__(256) void k_mean(
    const float* __restrict__ qkv, float* __restrict__ mean) {
  int bc = blockIdx.x;              // b*64 + c
  int b = bc >> 6, c = bc & 63;
  const float* src = qkv + ((size_t)b * 192 + c) * HWP;
  float s = 0.f;
  for (int i = threadIdx.x; i < HWP; i += 256) s += src[i];
  __shared__ float red[4];
  for (int off = 32; off > 0; off >>= 1) s += __shfl_down(s, off);
  int t = threadIdx.x;
  if ((t & 63) == 0) red[t >> 6] = s;
  __syncthreads();
  if (t == 0) mean[bc] = (red[0] + red[1] + red[2] + red[3]) * (1.f / 16384.f);
}

// ---------------- 3b: centered cov partials (chunks of 128) ----------------
__global__ __launch_bounds__(256) void k_covpart(
    const float* __restrict__ qkv, const float* __restrict__ mean,
    float* __restrict__ covp) {
  int blk = blockIdx.x;             // b*128 + chunk
  int b = blk >> 7, chunk = blk & 127;
  int e0 = chunk * 128;
  __shared__ float qc[64 * 129];    // +1 pad breaks stride conflicts
  int t = threadIdx.x;
  for (int i = 0; i < 32; ++i) {
    int f = i * 256 + t;
    int c = f >> 7, e = f & 127;
    qc[c * 129 + e] = qkv[((size_t)b * 192 + c) * HWP + e0 + e] - mean[b * 64 + c];
  }
  __syncthreads();
  int d = t & 63;
  int crow = t >> 6;                // wave-uniform
  float acc[16];
#pragma unroll
  for (int i = 0; i < 16; ++i) acc[i] = 0.f;
  for (int e = 0; e < 128; ++e) {
    float qd = qc[d * 129 + e];
#pragma unroll
    for (int i = 0; i < 16; ++i) {
      int c = crow + 4 * i;
      acc[i] = fmaf(qc[c * 129 + e], qd, acc[i]);
    }
  }
  float* dst = covp + (size_t)blk * 4096;
#pragma unroll
  for (int i = 0; i < 16; ++i) {
    int c = crow + 4 * i;
    dst[c * 64 + d] = acc[i];       // == dst[i*256 + t], coalesced
  }
}

// ---------------- 3b2: reduce cov partials over 128 chunks (coalesced) ----------------
__global__ __launch_bounds__(256) void k_covred(
    const float* __restrict__ covp, float* __restrict__ covs) {
  int blk = blockIdx.x;             // b*16 + j
  int b = blk >> 4;
  int pp = (blk & 15) * 256 + threadIdx.x;
  const float* src = covp + (size_t)b * 524288 + pp;
  float s = 0.f;
  for (int ch = 0; ch < 128; ++ch) s += src[ch * 4096];   // chunk order preserved
  covs[b * 4096 + pp] = s;
}

// ---------------- 3c: correlation-mean sim, stable rank ----------------
__global__ __launch_bounds__(256) void k_simsort(
    const float* __restrict__ covs_g, int* __restrict__ idx, int* __restrict__ inv) {
  int b = blockIdx.x;               // 4 blocks
  __shared__ float covs[4096];
  __shared__ float stds[64];
  __shared__ float sims[64];
  int t = threadIdx.x;
  for (int i = 0; i < 16; ++i) covs[i * 256 + t] = covs_g[b * 4096 + i * 256 + t];
  __syncthreads();
  if (t < 64) stds[t] = sqrtf(covs[t * 64 + t] + 1e-8f);
  __syncthreads();
  if (t < 64) {
    float s = 0.f;
    float sc = stds[t];
    for (int d2 = 0; d2 < 64; ++d2) {
      float denom = fmaxf(sc * stds[d2], 1e-8f);
      s += covs[d2 * 64 + t] / denom;   // symmetric matrix: bitwise equal to [t][d2]
    }
    sims[t] = s * (1.f / 64.f);
  }
  __syncthreads();
  if (t < 64) {
    float sv = sims[t];
    int r = 0;
    for (int d2 = 0; d2 < 64; ++d2) {
      float o = sims[d2];
      if (o > sv || (o == sv && d2 < t)) r++;
    }
    idx[b * 64 + r] = t;
    inv[b * 64 + t] = r;
  }
}

// ---------------- 7: halo block attention + gate, scatter to original channels ----------------
__global__ __launch_bounds__(64) void k_attn(
    const float* __restrict__ qkv, const int* __restrict__ idx,
    const float* __restrict__ gate_w, const float* __restrict__ gate_b,
    const float* __restrict__ temp, const float* __restrict__ rel_h,
    const float* __restrict__ rel_w, float* __restrict__ attn_out) {
  int bi = blockIdx.x;
  int head = bi & 3;
  int wj = (bi >> 2) & 15;
  int hi = (bi >> 6) & 15;
  int b = bi >> 10;
  __shared__ __align__(16) float kr[100 * 20];  // stride 20: 80B rows, 16B aligned
  __shared__ __align__(16) float vr[100 * 20];
  __shared__ float rn[100];
  __shared__ float gw[256];
  __shared__ float gb[16];
  __shared__ int chg[16];
  int t = threadIdx.x;
  if (t < 16) {
    chg[t] = idx[b * 64 + head * 16 + t];
    gb[t] = gate_b[head * 16 + t];
  }
  __syncthreads();
  const size_t bb = (size_t)b * 192 * HWP;
  // K/V halo load, consecutive lanes -> consecutive positions (coalesced rows)
  for (int i = 0; i < 25; ++i) {
    int f = i * 64 + t;               // 1600 = 16ch * 100pos
    int ch = f / 100;
    int pos = f - ch * 100;
    int py = pos / 10, px = pos - py * 10;
    int ky = hi * 8 + py - 1, kx = wj * 8 + px - 1;
    bool ok = (ky >= 0) && (ky < 128) && (kx >= 0) && (kx < 128);
    int sp = ky * 128 + kx;
    float kv = ok ? qkv[bb + (size_t)(64 + chg[ch]) * HWP + sp] : 0.f;
    float vv = ok ? qkv[bb + (size_t)(128 + chg[ch]) * HWP + sp] : 0.f;
    kv += (ch < 8) ? rel_h[(head * 10 + py) * 8 + ch]
                   : rel_w[(head * 10 + px) * 8 + (ch - 8)];
    kr[pos * 20 + ch] = kv;
    vr[pos * 20 + ch] = vv;
  }
  for (int i = 0; i < 4; ++i) {
    int f = i * 64 + t;
    if (f < 256) gw[f] = gate_w[head * 256 + f];
  }
  __syncthreads();
  if (t < 100) {
    float s = 0.f;
#pragma unroll
    for (int ch = 0; ch < 16; ++ch) { float v = kr[t * 20 + ch]; s += v * v; }
    rn[t] = 1.f / fmaxf(sqrtf(s), 1e-12f);
  }
  { // remaining 36 rows
    int t2 = t + 64;
    if (t2 < 100) {
      float s = 0.f;
#pragma unroll
      for (int ch = 0; ch < 16; ++ch) { float v = kr[t2 * 20 + ch]; s += v * v; }
      rn[t2] = 1.f / fmaxf(sqrtf(s), 1e-12f);
    }
  }
  __syncthreads();
  // per-query
  int qy = hi * 8 + (t >> 3), qx = wj * 8 + (t & 7);
  float q[16];
  float qs = 0.f;
#pragma unroll
  for (int ch = 0; ch < 16; ++ch) {
    q[ch] = qkv[bb + (size_t)chg[ch] * HWP + qy * 128 + qx];
    qs += q[ch] * q[ch];
  }
  float qn = 1.f / fmaxf(sqrtf(qs), 1e-12f);
  float T = expf(temp[head]);
  float out[16];
#pragma unroll
  for (int ch = 0; ch < 16; ++ch) out[ch] = 0.f;
  float wsum = 0.f;
  for (int kk = 0; kk < 100; ++kk) {
    const float4* kp = (const float4*)(kr + kk * 20);
    const float4* vp = (const float4*)(vr + kk * 20);
    float kv[16], vv[16];
    *(float4*)(kv + 0)  = kp[0]; *(float4*)(kv + 4)  = kp[1];
    *(float4*)(kv + 8)  = kp[2]; *(float4*)(kv + 12) = kp[3];
    *(float4*)(vv + 0)  = vp[0]; *(float4*)(vv + 4)  = vp[1];
    *(float4*)(vv + 8)  = vp[2]; *(float4*)(vv + 12) = vp[3];
    float dacc = 0.f;
#pragma unroll
    for (int ch = 0; ch < 16; ++ch) dacc = fmaf(q[ch], kv[ch], dacc);
    float d = dacc * qn * rn[kk] * T;
    float e = expf(d - T);            // shift by upper bound: exact softmax, no max pass
    wsum += e;
#pragma unroll
    for (int ch = 0; ch < 16; ++ch) out[ch] = fmaf(e, vv[ch], out[ch]);
  }
  float winv = 1.f / wsum;
#pragma unroll
  for (int o = 0; o < 16; ++o) {
    float gsv = gb[o];
#pragma unroll
    for (int c = 0; c < 16; ++c) gsv = fmaf(gw[o * 16 + c], q[c], gsv);
    float sig = 1.f / (1.f + expf(-gsv));
    attn_out[((size_t)b * 64 + chg[o]) * HWP + qy * 128 + qx] = out[o] * winv * sig;
  }
}

// ---------------- 8: mixed -> gating -> down -> up -> (+attn) -> proj ----------------
// One pixel per thread; 64-channel vector lives in a private LDS row (stride 65,
// 2-way bank aliasing = free). All 4 weight matrices staged to LDS once per block
// (12288 floats, 48 KB); compute reads are broadcast -> conflict-free. No
// inter-stage barriers (xs rows are thread-private).
__global__ __launch_bounds__(256) void k_post(
    const float* __restrict__ attn, const float* __restrict__ qkv,
    const float* __restrict__ gating_w, const float* __restrict__ gating_b,
    const float* __restrict__ down_w, const float* __restrict__ down_b,
    const float* __restrict__ up_w, const float* __restrict__ up_b,
    const float* __restrict__ proj_w, float* __restrict__ out3) {
  __shared__ float gTs[4096];   // gTs[d*64+o] = gating_w[o*64+d]
  __shared__ float pTs[4096];   // pTs[d*64+o] = proj_w[o*64+d]
  __shared__ float dTs[2048];   // dTs[d*32+o] = down_w[o*64+d]
  __shared__ float uTs[2048];   // uTs[d*64+o] = up_w[o*32+d]
  __shared__ float xs[256 * 65];
  int t = threadIdx.x;
  for (int i = t; i < 4096; i += 256) {
    int o = i >> 6, d = i & 63;
    gTs[d * 64 + o] = gating_w[i];
    pTs[d * 64 + o] = proj_w[i];
  }
  for (int i = t; i < 2048; i += 256) {
    int o = i >> 6, d = i & 63;     // down_w (32,64)
    dTs[d * 32 + o] = down_w[i];
    int o2 = i >> 5, d2 = i & 31;   // up_w (64,32)
    uTs[d2 * 64 + o2] = up_w[i];
  }
  size_t p = (size_t)blockIdx.x * 256 + t;
  int b = (int)(p >> 14);
  int pix = (int)(p & 16383);
  const float* ap = attn + (size_t)b * 64 * HWP + pix;
  const float* qp = qkv + (size_t)b * 192 * HWP + pix;
  float* op = out3 + (size_t)b * 64 * HWP + pix;
  int xb = t * 65;
  // mixed = attn_out + (q + k)   (cache un-permutes to q+k)
#pragma unroll
  for (int c = 0; c < 64; ++c)
    xs[xb + c] = ap[(size_t)c * HWP] + qp[(size_t)c * HWP] + qp[(size_t)(64 + c) * HWP];
  __syncthreads();   // weights visible (xs rows are thread-private, no hazard)
  // ---- gating conv + exact gelu, * mixed ----
  {
    float acc[64];
#pragma unroll
    for (int o = 0; o < 64; ++o) acc[o] = gating_b[o];
    for (int d = 0; d < 64; ++d) {
      float xv = xs[xb + d];
      const float4* wr = (const float4*)(gTs + d * 64);
#pragma unroll
      for (int o4 = 0; o4 < 16; ++o4) {
        float4 w = wr[o4];
        acc[o4 * 4 + 0] = fmaf(w.x, xv, acc[o4 * 4 + 0]);
        acc[o4 * 4 + 1] = fmaf(w.y, xv, acc[o4 * 4 + 1]);
        acc[o4 * 4 + 2] = fmaf(w.z, xv, acc[o4 * 4 + 2]);
        acc[o4 * 4 + 3] = fmaf(w.w, xv, acc[o4 * 4 + 3]);
      }
    }
#pragma unroll
    for (int o = 0; o < 64; ++o) {
      float a = acc[o];
      float ge = 0.5f * a * (1.f + erff(a * 0.70710678118654752f));
      xs[xb + o] = ge * xs[xb + o];
    }
  }
  // ---- down 64->32 ----
  {
    float acc[32];
#pragma unroll
    for (int o = 0; o < 32; ++o) acc[o] = down_b[o];
    for (int d = 0; d < 64; ++d) {
      float xv = xs[xb + d];
      const float4* wr = (const float4*)(dTs + d * 32);
#pragma unroll
      for (int o4 = 0; o4 < 8; ++o4) {
        float4 w = wr[o4];
        acc[o4 * 4 + 0] = fmaf(w.x, xv, acc[o4 * 4 + 0]);
        acc[o4 * 4 + 1] = fmaf(w.y, xv, acc[o4 * 4 + 1]);
        acc[o4 * 4 + 2] = fmaf(w.z, xv, acc[o4 * 4 + 2]);
        acc[o4 * 4 + 3] = fmaf(w.w, xv, acc[o4 * 4 + 3]);
      }
    }
#pragma unroll
    for (int o = 0; o < 32; ++o) xs[xb + o] = acc[o];
  }
  // ---- up 32->64, + attn residual ----
  {
    float acc[64];
#pragma unroll
    for (int o = 0; o < 64; ++o) acc[o] = up_b[o];
    for (int d = 0; d < 32; ++d) {
      float xv = xs[xb + d];
      const float4* wr = (const float4*)(uTs + d * 64);
#pragma unroll
      for (int o4 = 0; o4 < 16; ++o4) {
        float4 w = wr[o4];
        acc[o4 * 4 + 0] = fmaf(w.x, xv, acc[o4 * 4 + 0]);
        acc[o4 * 4 + 1] = fmaf(w.y, xv, acc[o4 * 4 + 1]);
        acc[o4 * 4 + 2] = fmaf(w.z, xv, acc[o4 * 4 + 2]);
        acc[o4 * 4 + 3] = fmaf(w.w, xv, acc[o4 * 4 + 3]);
      }
    }
#pragma unroll
    for (int o = 0; o < 64; ++o) xs[xb + o] = acc[o] + ap[(size_t)o * HWP];
  }
  // ---- proj (no bias) ----
  {
    float acc[64];
#pragma unroll
    for (int o = 0; o < 64; ++o) acc[o] = 0.f;
    for (int d = 0; d < 64; ++d) {
      float xv = xs[xb + d];
      const float4* wr = (const float4*)(pTs + d * 64);
#pragma unroll
      for (int o4 = 0; o4 < 16; ++o4) {
        float4 w = wr[o4];
        acc[o4 * 4 + 0] = fmaf(w.x, xv, acc[o4 * 4 + 0]);
        acc[o4 * 4 + 1] = fmaf(w.y, xv, acc[o4 * 4 + 1]);
        acc[o4 * 4 + 2] = fmaf(w.z, xv, acc[o4 * 4 + 2]);
        acc[o4 * 4 + 3] = fmaf(w.w, xv, acc[o4 * 4 + 3]);
      }
    }
#pragma unroll
    for (int c = 0; c < 64; ++c) op[(size_t)c * HWP] = acc[c];
  }
}

// ---------------- 9: dw3x3 reflect + bias + bilinear x2 (align-corners) ----------------
__global__ __launch_bounds__(256) void k_final(
    const float* __restrict__ out3, const float* __restrict__ lp_w,
    const float* __restrict__ lp_b, float* __restrict__ out) {
  int bi = blockIdx.x;                 // (b*64+ch)*8 + rt
  int rt = bi & 7;
  int bc = bi >> 3;
  int ch = bc & 63;
  int r0 = rt * 16;
  __shared__ float tin[20 * 128];      // input rows r0-2 .. r0+17 (reflected)
  __shared__ float tdw[18 * 128];      // dw rows r0-1 .. r0+16
  int t = threadIdx.x;
  const float* src = out3 + (size_t)bc * HWP;
  for (int i = 0; i < 10; ++i) {
    int f = i * 256 + t;               // 2560 exactly
    int r = f >> 7, xx = f & 127;
    int ry = r0 - 2 + r;
    ry = ry < 0 ? -ry : (ry > 127 ? 254 - ry : ry);
    tin[f] = src[ry * 128 + xx];
  }
  __syncthreads();
  float w0 = lp_w[ch * 9 + 0], w1 = lp_w[ch * 9 + 1], w2 = lp_w[ch * 9 + 2];
  float w3 = lp_w[ch * 9 + 3], w4 = lp_w[ch * 9 + 4], w5 = lp_w[ch * 9 + 5];
  float w6 = lp_w[ch * 9 + 6], w7 = lp_w[ch * 9 + 7], w8 = lp_w[ch * 9 + 8];
  float bias = lp_b[ch];
  for (int i = 0; i < 9; ++i) {
    int f = i * 256 + t;               // 2304 exactly
    int r = f >> 7, xx = f & 127;
    int xm = (xx == 0) ? 1 : xx - 1;
    int xp = (xx == 127) ? 126 : xx + 1;
    const float* r0p = tin + r * 128;
    const float* r1p = r0p + 128;
    const float* r2p = r1p + 128;
    float acc = bias;
    acc = fmaf(w0, r0p[xm], acc); acc = fmaf(w1, r0p[xx], acc); acc = fmaf(w2, r0p[xp], acc);
    acc = fmaf(w3, r1p[xm], acc); acc = fmaf(w4, r1p[xx], acc); acc = fmaf(w5, r1p[xp], acc);
    acc = fmaf(w6, r2p[xm], acc); acc = fmaf(w7, r2p[xx], acc); acc = fmaf(w8, r2p[xp], acc);
    tdw[f] = acc;
  }
  __syncthreads();
  const float s = (float)(127.0 / 255.0);
  float* dst = out + (size_t)bc * 65536;
  for (int i = 0; i < 32; ++i) {
    int f = i * 256 + t;               // 8192 exactly: rows 2r0..2r0+31, cols 0..255
    int vr = f >> 8, vx = f & 255;
    int v = 2 * r0 + vr;
    float cy = (float)v * s;
    int ly = (int)floorf(cy); if (ly > 126) ly = 126;
    float wy = cy - (float)ly;
    float cx = (float)vx * s;
    int lx = (int)floorf(cx); if (lx > 126) lx = 126;
    float wx = cx - (float)lx;
    int lr = ly - r0 + 1;              // tdw row index
    float a  = tdw[lr * 128 + lx];
    float bq = tdw[lr * 128 + lx + 1];
    float c2 = tdw[(lr + 1) * 128 + lx];
    float d2 = tdw[(lr + 1) * 128 + lx + 1];
    float t0 = a  * (1.f - wy) + c2 * wy;   // y-lerp first (matches ref order)
    float t1 = bq * (1.f - wy) + d2 * wy;
    dst[v * 256 + vx] = t0 * (1.f - wx) + t1 * wx;
  }
}

extern "C" void kernel_launch(void* const* d_in, const int* in_sizes, int n_in,
                              void* d_out, int out_size, void* d_ws, size_t ws_size,
                              hipStream_t stream) {
  (void)in_sizes; (void)n_in; (void)out_size; (void)ws_size;
  const float* x        = (const float*)d_in[0];
  const float* qkv_w    = (const float*)d_in[1];
  const float* lce_w    = (const float*)d_in[2];
  const float* gate_w   = (const float*)d_in[3];
  const float* gate_b   = (const float*)d_in[4];
  const float* temp     = (const float*)d_in[5];
  const float* rel_h    = (const float*)d_in[6];
  const float* rel_w    = (const float*)d_in[7];
  const float* down_w   = (const float*)d_in[8];
  const float* down_b   = (const float*)d_in[9];
  const float* up_w     = (const float*)d_in[10];
  const float* up_b     = (const float*)d_in[11];
  const float* gating_w = (const float*)d_in[12];
  const float* gating_b = (const float*)d_in[13];
  const float* proj_w   = (const float*)d_in[14];
  const float* lp_w     = (const float*)d_in[15];
  const float* lp_b     = (const float*)d_in[16];
  float* fws = (float*)d_ws;
  float* outp = (float*)d_out;

  float* pre  = fws + PRE_OFF;
  float* qkv  = fws + QKV_OFF;
  float* attn = fws + ATTN_OFF;
  float* out3 = fws + OUT3_OFF;
  float* covp = fws + COVP_OFF;
  float* mean = fws + MEAN_OFF;
  int* idx = (int*)(fws + IDX_OFF);
  int* inv = (int*)(fws + INV_OFF);
  float* covs = fws + COVS_OFF;

  k_pool_conv<<<1024, 256, 0, stream>>>(x, qkv_w, pre);
  k_dw3x3_zero<<<49152, 256, 0, stream>>>(pre, lce_w, qkv);
  k_mean<<<256, 256, 0, stream>>>(qkv, mean);
  k_covpart<<<512, 256, 0, stream>>>(qkv, mean, covp);
  k_covred<<<64, 256, 0, stream>>>(covp, covs);
  k_simsort<<<4, 256, 0, stream>>>(covs, idx, inv);
  k_attn<<<4096, 64, 0, stream>>>(qkv, idx, gate_w, gate_b, temp, rel_h, rel_w, attn);
  k_post<<<256, 256, 0, stream>>>(attn, qkv, gating_w, gating_b, down_w, down_b,
                                  up_w, up_b, proj_w, out3);
  k_final<<<2048, 256, 0, stream>>>(out3, lp_w, lp_b, outp);
  (void)inv;
}

// Round 4
// 496.114 us; speedup vs baseline: 1.3256x; 1.1247x over previous
//
#include <hip/hip_runtime.h>
#include <math.h>

#define HWP 16384   // 128*128 pooled plane

// ---------------- workspace layout (float offsets) ----------------
static const size_t PRE_OFF  = 0;          // 4*192*16384 = 12,582,912
static const size_t QKV_OFF  = 12582912;   // 12,582,912
// wT lives at the START of the QKV region: written by k_prep_wt, read only by
// k_pool_conv (which writes PRE only), then overwritten by k_dw3x3_zero. No alias.
static const size_t WT_OFF   = QKV_OFF;    // 12,288 floats
// after dw3x3, PRE region is dead -> reuse:
static const size_t ATTN_OFF = 0;          // 4,194,304
static const size_t OUT3_OFF = 4194304;    // 4,194,304
static const size_t COVP_OFF = 8388608;    // 4*128*4096 = 2,097,152
static const size_t MEAN_OFF = 10485760;   // 256
static const size_t IDX_OFF  = 10486016;   // 256 ints
static const size_t INV_OFF  = 10486272;   // 256 ints
static const size_t COVS_OFF = 10486528;   // 4*4096 = 16,384

// ---------------- 0: transpose qkv_w -> wT[c*192+o] ----------------
__global__ __launch_bounds__(256) void k_prep_wt(
    const float* __restrict__ qkv_w, float* __restrict__ wT) {
  int i = blockIdx.x * 256 + threadIdx.x;   // 12288
  int o = i >> 6, c = i & 63;
  wT[c * 192 + o] = qkv_w[i];
}

// ---------------- 1: maxpool2 + conv1x1 (x -> qkv_pre) ----------------
// Each wave owns a CONTIGUOUS slab of 48 output channels; weights are read
// c-major via wave-uniform base (readfirstlane) -> wide s_load batches instead
// of 12K scattered s_load_dword per block (the round-2 latency wall).
__global__ __launch_bounds__(256) void k_pool_conv(
    const float* __restrict__ x, const float* __restrict__ wT,
    float* __restrict__ pre) {
  int b = blockIdx.x >> 8;          // 256 tiles / batch
  int pix0 = (blockIdx.x & 255) * 64;
  __shared__ float xt[64 * 64];     // [c][p]
  int t = threadIdx.x;
  for (int i = 0; i < 16; ++i) {
    int f = i * 256 + t;
    int c = f >> 6, p = f & 63;
    int pix = pix0 + p;
    int y = pix >> 7, xx = pix & 127;
    const float* src = x + ((size_t)(b * 64 + c) * 65536) + (2 * y) * 256 + 2 * xx;
    float2 v01 = *(const float2*)src;
    float2 v23 = *(const float2*)(src + 256);
    xt[c * 64 + p] = fmaxf(fmaxf(v01.x, v01.y), fmaxf(v23.x, v23.y));
  }
  __syncthreads();
  int p = t & 63;
  int obase = __builtin_amdgcn_readfirstlane((t >> 6) * 48);  // wave-uniform
  const float* wbase = wT + obase;
  float acc[48];
#pragma unroll
  for (int j = 0; j < 48; ++j) acc[j] = 0.f;
  for (int c = 0; c < 64; ++c) {
    float xv = xt[c * 64 + p];
    const float* wc = wbase + c * 192;    // uniform -> s_load_dwordx16 x3
#pragma unroll
    for (int j = 0; j < 48; ++j) acc[j] = fmaf(wc[j], xv, acc[j]);
  }
  float* dst = pre + ((size_t)b * 192 + obase) * HWP + pix0 + p;
#pragma unroll
  for (int j = 0; j < 48; ++j) dst[(size_t)j * HWP] = acc[j];
}

// ---------------- 2: depthwise 3x3, zero pad (pre -> qkv) ----------------
__global__ __launch_bounds__(256) void k_dw3x3_zero(
    const float* __restrict__ pre, const float* __restrict__ lce_w,
    float* __restrict__ qkv) {
  int gid = blockIdx.x * 256 + threadIdx.x;   // 4*192*16384 total
  int pix = gid & (HWP - 1);
  int bc = gid >> 14;
  int ch = bc % 192;
  int y = pix >> 7, xx = pix & 127;
  const float* w = lce_w + ch * 9;
  const float* base = pre + (size_t)bc * HWP;
  float acc = 0.f;
#pragma unroll
  for (int dy = -1; dy <= 1; ++dy) {
    int yy = y + dy;
    if (yy < 0 || yy > 127) continue;
#pragma unroll
    for (int dx = -1; dx <= 1; ++dx) {
      int xc = xx + dx;
      if (xc < 0 || xc > 127) continue;
      acc = fmaf(w[(dy + 1) * 3 + dx + 1], base[yy * 128 + xc], acc);
    }
  }
  qkv[gid] = acc;
}

// ---------------- 3a: per-channel mean of q ----------------
__global__ __launch_bounds__(256) void k_mean(
    const float* __restrict__ qkv, float* __restrict__ mean) {
  int bc = blockIdx.x;              // b*64 + c
  int b = bc >> 6, c = bc & 63;
  const float* src = qkv + ((size_t)b * 192 + c) * HWP;
  float s = 0.f;
  for (int i = threadIdx.x; i < HWP; i += 256) s += src[i];
  __shared__ float red[4];
  for (int off = 32; off > 0; off >>= 1) s += __shfl_down(s, off);
  int t = threadIdx.x;
  if ((t & 63) == 0) red[t >> 6] = s;
  __syncthreads();
  if (t == 0) mean[bc] = (red[0] + red[1] + red[2] + red[3]) * (1.f / 16384.f);
}

// ---------------- 3b: centered cov partials (chunks of 128) ----------------
__global__ __launch_bounds__(256) void k_covpart(
    const float* __restrict__ qkv, const float* __restrict__ mean,
    float* __restrict__ covp) {
  int blk = blockIdx.x;             // b*128 + chunk
  int b = blk >> 7, chunk = blk & 127;
  int e0 = chunk * 128;
  __shared__ float qc[64 * 129];    // +1 pad breaks stride conflicts
  int t = threadIdx.x;
  for (int i = 0; i < 32; ++i) {
    int f = i * 256 + t;
    int c = f >> 7, e = f & 127;
    qc[c * 129 + e] = qkv[((size_t)b * 192 + c) * HWP + e0 + e] - mean[b * 64 + c];
  }
  __syncthreads();
  int d = t & 63;
  int crow = t >> 6;                // wave-uniform
  float acc[16];
#pragma unroll
  for (int i = 0; i < 16; ++i) acc[i] = 0.f;
  for (int e = 0; e < 128; ++e) {
    float qd = qc[d * 129 + e];
#pragma unroll
    for (int i = 0; i < 16; ++i) {
      int c = crow + 4 * i;
      acc[i] = fmaf(qc[c * 129 + e], qd, acc[i]);
    }
  }
  float* dst = covp + (size_t)blk * 4096;
#pragma unroll
  for (int i = 0; i < 16; ++i) {
    int c = crow + 4 * i;
    dst[c * 64 + d] = acc[i];       // == dst[i*256 + t], coalesced
  }
}

// ---------------- 3b2: reduce cov partials over 128 chunks (coalesced) ----------------
__global__ __launch_bounds__(256) void k_covred(
    const float* __restrict__ covp, float* __restrict__ covs) {
  int blk = blockIdx.x;             // b*16 + j
  int b = blk >> 4;
  int pp = (blk & 15) * 256 + threadIdx.x;
  const float* src = covp + (size_t)b * 524288 + pp;
  float s = 0.f;
  for (int ch = 0; ch < 128; ++ch) s += src[ch * 4096];   // chunk order preserved
  covs[b * 4096 + pp] = s;
}

// ---------------- 3c: correlation-mean sim, stable rank ----------------
__global__ __launch_bounds__(256) void k_simsort(
    const float* __restrict__ covs_g, int* __restrict__ idx, int* __restrict__ inv) {
  int b = blockIdx.x;               // 4 blocks
  __shared__ float covs[4096];
  __shared__ float stds[64];
  __shared__ float sims[64];
  int t = threadIdx.x;
  for (int i = 0; i < 16; ++i) covs[i * 256 + t] = covs_g[b * 4096 + i * 256 + t];
  __syncthreads();
  if (t < 64) stds[t] = sqrtf(covs[t * 64 + t] + 1e-8f);
  __syncthreads();
  if (t < 64) {
    float s = 0.f;
    float sc = stds[t];
    for (int d2 = 0; d2 < 64; ++d2) {
      float denom = fmaxf(sc * stds[d2], 1e-8f);
      s += covs[d2 * 64 + t] / denom;   // symmetric matrix: bitwise equal to [t][d2]
    }
    sims[t] = s * (1.f / 64.f);
  }
  __syncthreads();
  if (t < 64) {
    float sv = sims[t];
    int r = 0;
    for (int d2 = 0; d2 < 64; ++d2) {
      float o = sims[d2];
      if (o > sv || (o == sv && d2 < t)) r++;
    }
    idx[b * 64 + r] = t;
    inv[b * 64 + t] = r;
  }
}

// ---------------- 7: halo block attention + gate, scatter to original channels ----------------
__global__ __launch_bounds__(64) void k_attn(
    const float* __restrict__ qkv, const int* __restrict__ idx,
    const float* __restrict__ gate_w, const float* __restrict__ gate_b,
    const float* __restrict__ temp, const float* __restrict__ rel_h,
    const float* __restrict__ rel_w, float* __restrict__ attn_out) {
  int bi = blockIdx.x;
  int head = bi & 3;
  int wj = (bi >> 2) & 15;
  int hi = (bi >> 6) & 15;
  int b = bi >> 10;
  __shared__ __align__(16) float kr[100 * 20];  // stride 20: 80B rows, 16B aligned
  __shared__ __align__(16) float vr[100 * 20];
  __shared__ float rn[100];
  __shared__ float gw[256];
  __shared__ float gb[16];
  __shared__ int chg[16];
  int t = threadIdx.x;
  if (t < 16) {
    chg[t] = idx[b * 64 + head * 16 + t];
    gb[t] = gate_b[head * 16 + t];
  }
  __syncthreads();
  const size_t bb = (size_t)b * 192 * HWP;
  // K/V halo load, consecutive lanes -> consecutive positions (coalesced rows)
  for (int i = 0; i < 25; ++i) {
    int f = i * 64 + t;               // 1600 = 16ch * 100pos
    int ch = f / 100;
    int pos = f - ch * 100;
    int py = pos / 10, px = pos - py * 10;
    int ky = hi * 8 + py - 1, kx = wj * 8 + px - 1;
    bool ok = (ky >= 0) && (ky < 128) && (kx >= 0) && (kx < 128);
    int sp = ky * 128 + kx;
    float kv = ok ? qkv[bb + (size_t)(64 + chg[ch]) * HWP + sp] : 0.f;
    float vv = ok ? qkv[bb + (size_t)(128 + chg[ch]) * HWP + sp] : 0.f;
    kv += (ch < 8) ? rel_h[(head * 10 + py) * 8 + ch]
                   : rel_w[(head * 10 + px) * 8 + (ch - 8)];
    kr[pos * 20 + ch] = kv;
    vr[pos * 20 + ch] = vv;
  }
  for (int i = 0; i < 4; ++i) {
    int f = i * 64 + t;
    if (f < 256) gw[f] = gate_w[head * 256 + f];
  }
  __syncthreads();
  if (t < 100) {
    float s = 0.f;
#pragma unroll
    for (int ch = 0; ch < 16; ++ch) { float v = kr[t * 20 + ch]; s += v * v; }
    rn[t] = 1.f / fmaxf(sqrtf(s), 1e-12f);
  }
  { // remaining 36 rows
    int t2 = t + 64;
    if (t2 < 100) {
      float s = 0.f;
#pragma unroll
      for (int ch = 0; ch < 16; ++ch) { float v = kr[t2 * 20 + ch]; s += v * v; }
      rn[t2] = 1.f / fmaxf(sqrtf(s), 1e-12f);
    }
  }
  __syncthreads();
  // per-query
  int qy = hi * 8 + (t >> 3), qx = wj * 8 + (t & 7);
  float q[16];
  float qs = 0.f;
#pragma unroll
  for (int ch = 0; ch < 16; ++ch) {
    q[ch] = qkv[bb + (size_t)chg[ch] * HWP + qy * 128 + qx];
    qs += q[ch] * q[ch];
  }
  float qn = 1.f / fmaxf(sqrtf(qs), 1e-12f);
  float T = expf(temp[head]);
  float out[16];
#pragma unroll
  for (int ch = 0; ch < 16; ++ch) out[ch] = 0.f;
  float wsum = 0.f;
  for (int kk = 0; kk < 100; ++kk) {
    const float4* kp = (const float4*)(kr + kk * 20);
    const float4* vp = (const float4*)(vr + kk * 20);
    float kv[16], vv[16];
    *(float4*)(kv + 0)  = kp[0]; *(float4*)(kv + 4)  = kp[1];
    *(float4*)(kv + 8)  = kp[2]; *(float4*)(kv + 12) = kp[3];
    *(float4*)(vv + 0)  = vp[0]; *(float4*)(vv + 4)  = vp[1];
    *(float4*)(vv + 8)  = vp[2]; *(float4*)(vv + 12) = vp[3];
    float dacc = 0.f;
#pragma unroll
    for (int ch = 0; ch < 16; ++ch) dacc = fmaf(q[ch], kv[ch], dacc);
    float d = dacc * qn * rn[kk] * T;
    float e = expf(d - T);            // shift by upper bound: exact softmax, no max pass
    wsum += e;
#pragma unroll
    for (int ch = 0; ch < 16; ++ch) out[ch] = fmaf(e, vv[ch], out[ch]);
  }
  float winv = 1.f / wsum;
#pragma unroll
  for (int o = 0; o < 16; ++o) {
    float gsv = gb[o];
#pragma unroll
    for (int c = 0; c < 16; ++c) gsv = fmaf(gw[o * 16 + c], q[c], gsv);
    float sig = 1.f / (1.f + expf(-gsv));
    attn_out[((size_t)b * 64 + chg[o]) * HWP + qy * 128 + qx] = out[o] * winv * sig;
  }
}

// ---------------- 8: mixed -> gating -> down -> up -> (+attn) -> proj ----------------
__global__ __launch_bounds__(256) void k_post(
    const float* __restrict__ attn, const float* __restrict__ qkv,
    const float* __restrict__ gating_w, const float* __restrict__ gating_b,
    const float* __restrict__ down_w, const float* __restrict__ down_b,
    const float* __restrict__ up_w, const float* __restrict__ up_b,
    const float* __restrict__ proj_w, float* __restrict__ out3) {
  __shared__ float gTs[4096];   // gTs[d*64+o] = gating_w[o*64+d]
  __shared__ float pTs[4096];   // pTs[d*64+o] = proj_w[o*64+d]
  __shared__ float dTs[2048];   // dTs[d*32+o] = down_w[o*64+d]
  __shared__ float uTs[2048];   // uTs[d*64+o] = up_w[o*32+d]
  __shared__ float xs[256 * 65];
  int t = threadIdx.x;
  for (int i = t; i < 4096; i += 256) {
    int o = i >> 6, d = i & 63;
    gTs[d * 64 + o] = gating_w[i];
    pTs[d * 64 + o] = proj_w[i];
  }
  for (int i = t; i < 2048; i += 256) {
    int o = i >> 6, d = i & 63;     // down_w (32,64)
    dTs[d * 32 + o] = down_w[i];
    int o2 = i >> 5, d2 = i & 31;   // up_w (64,32)
    uTs[d2 * 64 + o2] = up_w[i];
  }
  size_t p = (size_t)blockIdx.x * 256 + t;
  int b = (int)(p >> 14);
  int pix = (int)(p & 16383);
  const float* ap = attn + (size_t)b * 64 * HWP + pix;
  const float* qp = qkv + (size_t)b * 192 * HWP + pix;
  float* op = out3 + (size_t)b * 64 * HWP + pix;
  int xb = t * 65;
  // mixed = attn_out + (q + k)   (cache un-permutes to q+k)
#pragma unroll
  for (int c = 0; c < 64; ++c)
    xs[xb + c] = ap[(size_t)c * HWP] + qp[(size_t)c * HWP] + qp[(size_t)(64 + c) * HWP];
  __syncthreads();   // weights visible (xs rows are thread-private, no hazard)
  // ---- gating conv + exact gelu, * mixed ----
  {
    float acc[64];
#pragma unroll
    for (int o = 0; o < 64; ++o) acc[o] = gating_b[o];
    for (int d = 0; d < 64; ++d) {
      float xv = xs[xb + d];
      const float4* wr = (const float4*)(gTs + d * 64);
#pragma unroll
      for (int o4 = 0; o4 < 16; ++o4) {
        float4 w = wr[o4];
        acc[o4 * 4 + 0] = fmaf(w.x, xv, acc[o4 * 4 + 0]);
        acc[o4 * 4 + 1] = fmaf(w.y, xv, acc[o4 * 4 + 1]);
        acc[o4 * 4 + 2] = fmaf(w.z, xv, acc[o4 * 4 + 2]);
        acc[o4 * 4 + 3] = fmaf(w.w, xv, acc[o4 * 4 + 3]);
      }
    }
#pragma unroll
    for (int o = 0; o < 64; ++o) {
      float a = acc[o];
      float ge = 0.5f * a * (1.f + erff(a * 0.70710678118654752f));
      xs[xb + o] = ge * xs[xb + o];
    }
  }
  // ---- down 64->32 ----
  {
    float acc[32];
#pragma unroll
    for (int o = 0; o < 32; ++o) acc[o] = down_b[o];
    for (int d = 0; d < 64; ++d) {
      float xv = xs[xb + d];
      const float4* wr = (const float4*)(dTs + d * 32);
#pragma unroll
      for (int o4 = 0; o4 < 8; ++o4) {
        float4 w = wr[o4];
        acc[o4 * 4 + 0] = fmaf(w.x, xv, acc[o4 * 4 + 0]);
        acc[o4 * 4 + 1] = fmaf(w.y, xv, acc[o4 * 4 + 1]);
        acc[o4 * 4 + 2] = fmaf(w.z, xv, acc[o4 * 4 + 2]);
        acc[o4 * 4 + 3] = fmaf(w.w, xv, acc[o4 * 4 + 3]);
      }
    }
#pragma unroll
    for (int o = 0; o < 32; ++o) xs[xb + o] = acc[o];
  }
  // ---- up 32->64, + attn residual ----
  {
    float acc[64];
#pragma unroll
    for (int o = 0; o < 64; ++o) acc[o] = up_b[o];
    for (int d = 0; d < 32; ++d) {
      float xv = xs[xb + d];
      const float4* wr = (const float4*)(uTs + d * 64);
#pragma unroll
      for (int o4 = 0; o4 < 16; ++o4) {
        float4 w = wr[o4];
        acc[o4 * 4 + 0] = fmaf(w.x, xv, acc[o4 * 4 + 0]);
        acc[o4 * 4 + 1] = fmaf(w.y, xv, acc[o4 * 4 + 1]);
        acc[o4 * 4 + 2] = fmaf(w.z, xv, acc[o4 * 4 + 2]);
        acc[o4 * 4 + 3] = fmaf(w.w, xv, acc[o4 * 4 + 3]);
      }
    }
#pragma unroll
    for (int o = 0; o < 64; ++o) xs[xb + o] = acc[o] + ap[(size_t)o * HWP];
  }
  // ---- proj (no bias) ----
  {
    float acc[64];
#pragma unroll
    for (int o = 0; o < 64; ++o) acc[o] = 0.f;
    for (int d = 0; d < 64; ++d) {
      float xv = xs[xb + d];
      const float4* wr = (const float4*)(pTs + d * 64);
#pragma unroll
      for (int o4 = 0; o4 < 16; ++o4) {
        float4 w = wr[o4];
        acc[o4 * 4 + 0] = fmaf(w.x, xv, acc[o4 * 4 + 0]);
        acc[o4 * 4 + 1] = fmaf(w.y, xv, acc[o4 * 4 + 1]);
        acc[o4 * 4 + 2] = fmaf(w.z, xv, acc[o4 * 4 + 2]);
        acc[o4 * 4 + 3] = fmaf(w.w, xv, acc[o4 * 4 + 3]);
      }
    }
#pragma unroll
    for (int c = 0; c < 64; ++c) op[(size_t)c * HWP] = acc[c];
  }
}

// ---------------- 9: dw3x3 reflect + bias + bilinear x2 (align-corners) ----------------
__global__ __launch_bounds__(256) void k_final(
    const float* __restrict__ out3, const float* __restrict__ lp_w,
    const float* __restrict__ lp_b, float* __restrict__ out) {
  int bi = blockIdx.x;                 // (b*64+ch)*8 + rt
  int rt = bi & 7;
  int bc = bi >> 3;
  int ch = bc & 63;
  int r0 = rt * 16;
  __shared__ float tin[20 * 128];      // input rows r0-2 .. r0+17 (reflected)
  __shared__ float tdw[18 * 128];      // dw rows r0-1 .. r0+16
  int t = threadIdx.x;
  const float* src = out3 + (size_t)bc * HWP;
  for (int i = 0; i < 10; ++i) {
    int f = i * 256 + t;               // 2560 exactly
    int r = f >> 7, xx = f & 127;
    int ry = r0 - 2 + r;
    ry = ry < 0 ? -ry : (ry > 127 ? 254 - ry : ry);
    tin[f] = src[ry * 128 + xx];
  }
  __syncthreads();
  float w0 = lp_w[ch * 9 + 0], w1 = lp_w[ch * 9 + 1], w2 = lp_w[ch * 9 + 2];
  float w3 = lp_w[ch * 9 + 3], w4 = lp_w[ch * 9 + 4], w5 = lp_w[ch * 9 + 5];
  float w6 = lp_w[ch * 9 + 6], w7 = lp_w[ch * 9 + 7], w8 = lp_w[ch * 9 + 8];
  float bias = lp_b[ch];
  for (int i = 0; i < 9; ++i) {
    int f = i * 256 + t;               // 2304 exactly
    int r = f >> 7, xx = f & 127;
    int xm = (xx == 0) ? 1 : xx - 1;
    int xp = (xx == 127) ? 126 : xx + 1;
    const float* r0p = tin + r * 128;
    const float* r1p = r0p + 128;
    const float* r2p = r1p + 128;
    float acc = bias;
    acc = fmaf(w0, r0p[xm], acc); acc = fmaf(w1, r0p[xx], acc); acc = fmaf(w2, r0p[xp], acc);
    acc = fmaf(w3, r1p[xm], acc); acc = fmaf(w4, r1p[xx], acc); acc = fmaf(w5, r1p[xp], acc);
    acc = fmaf(w6, r2p[xm], acc); acc = fmaf(w7, r2p[xx], acc); acc = fmaf(w8, r2p[xp], acc);
    tdw[f] = acc;
  }
  __syncthreads();
  const float s = (float)(127.0 / 255.0);
  float* dst = out + (size_t)bc * 65536;
  for (int i = 0; i < 32; ++i) {
    int f = i * 256 + t;               // 8192 exactly: rows 2r0..2r0+31, cols 0..255
    int vr = f >> 8, vx = f & 255;
    int v = 2 * r0 + vr;
    float cy = (float)v * s;
    int ly = (int)floorf(cy); if (ly > 126) ly = 126;
    float wy = cy - (float)ly;
    float cx = (float)vx * s;
    int lx = (int)floorf(cx); if (lx > 126) lx = 126;
    float wx = cx - (float)lx;
    int lr = ly - r0 + 1;              // tdw row index
    float a  = tdw[lr * 128 + lx];
    float bq = tdw[lr * 128 + lx + 1];
    float c2 = tdw[(lr + 1) * 128 + lx];
    float d2 = tdw[(lr + 1) * 128 + lx + 1];
    float t0 = a  * (1.f - wy) + c2 * wy;   // y-lerp first (matches ref order)
    float t1 = bq * (1.f - wy) + d2 * wy;
    dst[v * 256 + vx] = t0 * (1.f - wx) + t1 * wx;
  }
}

extern "C" void kernel_launch(void* const* d_in, const int* in_sizes, int n_in,
                              void* d_out, int out_size, void* d_ws, size_t ws_size,
                              hipStream_t stream) {
  (void)in_sizes; (void)n_in; (void)out_size; (void)ws_size;
  const float* x        = (const float*)d_in[0];
  const float* qkv_w    = (const float*)d_in[1];
  const float* lce_w    = (const float*)d_in[2];
  const float* gate_w   = (const float*)d_in[3];
  const float* gate_b   = (const float*)d_in[4];
  const float* temp     = (const float*)d_in[5];
  const float* rel_h    = (const float*)d_in[6];
  const float* rel_w    = (const float*)d_in[7];
  const float* down_w   = (const float*)d_in[8];
  const float* down_b   = (const float*)d_in[9];
  const float* up_w     = (const float*)d_in[10];
  const float* up_b     = (const float*)d_in[11];
  const float* gating_w = (const float*)d_in[12];
  const float* gating_b = (const float*)d_in[13];
  const float* proj_w   = (const float*)d_in[14];
  const float* lp_w     = (const float*)d_in[15];
  const float* lp_b     = (const float*)d_in[16];
  float* fws = (float*)d_ws;
  float* outp = (float*)d_out;

  float* pre  = fws + PRE_OFF;
  float* qkv  = fws + QKV_OFF;
  float* attn = fws + ATTN_OFF;
  float* out3 = fws + OUT3_OFF;
  float* covp = fws + COVP_OFF;
  float* mean = fws + MEAN_OFF;
  int* idx = (int*)(fws + IDX_OFF);
  int* inv = (int*)(fws + INV_OFF);
  float* covs = fws + COVS_OFF;
  float* wT   = fws + WT_OFF;

  k_prep_wt<<<48, 256, 0, stream>>>(qkv_w, wT);
  k_pool_conv<<<1024, 256, 0, stream>>>(x, wT, pre);
  k_dw3x3_zero<<<49152, 256, 0, stream>>>(pre, lce_w, qkv);
  k_mean<<<256, 256, 0, stream>>>(qkv, mean);
  k_covpart<<<512, 256, 0, stream>>>(qkv, mean, covp);
  k_covred<<<64, 256, 0, stream>>>(covp, covs);
  k_simsort<<<4, 256, 0, stream>>>(covs, idx, inv);
  k_attn<<<4096, 64, 0, stream>>>(qkv, idx, gate_w, gate_b, temp, rel_h, rel_w, attn);
  k_post<<<256, 256, 0, stream>>>(attn, qkv, gating_w, gating_b, down_w, down_b,
                                  up_w, up_b, proj_w, out3);
  k_final<<<2048, 256, 0, stream>>>(out3, lp_w, lp_b, outp);
  (void)inv;
}

// Round 5
// 453.905 us; speedup vs baseline: 1.4489x; 1.0930x over previous
//
#include <hip/hip_runtime.h>
#include <math.h>

#define HWP 16384   // 128*128 pooled plane

// ---------------- workspace layout (float offsets) ----------------
static const size_t PRE_OFF  = 0;          // 4*192*16384 = 12,582,912
static const size_t QKV_OFF  = 12582912;   // 12,582,912
// wT lives at the START of the QKV region: written by k_prep_wt, read only by
// k_pool_conv (which writes PRE only), then overwritten by k_dw3x3_zero. No alias.
static const size_t WT_OFF   = QKV_OFF;    // 12,288 floats
// after dw3x3, PRE region is dead -> reuse:
static const size_t ATTN_OFF = 0;          // 4,194,304
static const size_t OUT3_OFF = 4194304;    // 4,194,304
static const size_t COVP_OFF = 8388608;    // 4*128*4096 = 2,097,152
static const size_t MEAN_OFF = 10485760;   // 256
static const size_t IDX_OFF  = 10486016;   // 256 ints
static const size_t INV_OFF  = 10486272;   // 256 ints
static const size_t COVS_OFF = 10486528;   // 4*4096 -> ends 10,502,912
// transposed MLP weights: dead-PRE region, written by k_prep2 AFTER dw3x3
// (same-stream serialization), read by k_post. All < 12,582,912.
static const size_t GT2_OFF  = 10502912;   // 4096
static const size_t DT2_OFF  = 10507008;   // 2048
static const size_t UT2_OFF  = 10509056;   // 2048
static const size_t PT2_OFF  = 10511104;   // 4096 -> ends 10,515,200

// ---------------- 0: transpose qkv_w -> wT[c*192+o] ----------------
__global__ __launch_bounds__(256) void k_prep_wt(
    const float* __restrict__ qkv_w, float* __restrict__ wT) {
  int i = blockIdx.x * 256 + threadIdx.x;   // 12288
  int o = i >> 6, c = i & 63;
  wT[c * 192 + o] = qkv_w[i];
}

// ---------------- 0b: transpose MLP weights to d-major ----------------
__global__ __launch_bounds__(256) void k_prep2(
    const float* __restrict__ gating_w, const float* __restrict__ down_w,
    const float* __restrict__ up_w, const float* __restrict__ proj_w,
    float* __restrict__ gT, float* __restrict__ dT,
    float* __restrict__ uT, float* __restrict__ pT) {
  int t = blockIdx.x * 256 + threadIdx.x;
  if (t < 4096) {
    int o = t >> 6, d = t & 63;
    gT[d * 64 + o] = gating_w[t];
    pT[d * 64 + o] = proj_w[t];
  }
  if (t < 2048) {
    int o = t >> 6, d = t & 63;      // down_w (32,64)
    dT[d * 32 + o] = down_w[t];
    int o2 = t >> 5, d2 = t & 31;    // up_w (64,32)
    uT[d2 * 64 + o2] = up_w[t];
  }
}

// ---------------- 1: maxpool2 + conv1x1 (x -> qkv_pre) ----------------
__global__ __launch_bounds__(256) void k_pool_conv(
    const float* __restrict__ x, const float* __restrict__ wT,
    float* __restrict__ pre) {
  int b = blockIdx.x >> 8;          // 256 tiles / batch
  int pix0 = (blockIdx.x & 255) * 64;
  __shared__ float xt[64 * 64];     // [c][p]
  int t = threadIdx.x;
  for (int i = 0; i < 16; ++i) {
    int f = i * 256 + t;
    int c = f >> 6, p = f & 63;
    int pix = pix0 + p;
    int y = pix >> 7, xx = pix & 127;
    const float* src = x + ((size_t)(b * 64 + c) * 65536) + (2 * y) * 256 + 2 * xx;
    float2 v01 = *(const float2*)src;
    float2 v23 = *(const float2*)(src + 256);
    xt[c * 64 + p] = fmaxf(fmaxf(v01.x, v01.y), fmaxf(v23.x, v23.y));
  }
  __syncthreads();
  int p = t & 63;
  int obase = __builtin_amdgcn_readfirstlane((t >> 6) * 48);  // wave-uniform
  const float* wbase = wT + obase;
  float acc[48];
#pragma unroll
  for (int j = 0; j < 48; ++j) acc[j] = 0.f;
  for (int c = 0; c < 64; ++c) {
    float xv = xt[c * 64 + p];
    const float* wc = wbase + c * 192;    // uniform -> s_load_dwordx16 x3
#pragma unroll
    for (int j = 0; j < 48; ++j) acc[j] = fmaf(wc[j], xv, acc[j]);
  }
  float* dst = pre + ((size_t)b * 192 + obase) * HWP + pix0 + p;
#pragma unroll
  for (int j = 0; j < 48; ++j) dst[(size_t)j * HWP] = acc[j];
}

// ---------------- 2: depthwise 3x3, zero pad (pre -> qkv) ----------------
__global__ __launch_bounds__(256) void k_dw3x3_zero(
    const float* __restrict__ pre, const float* __restrict__ lce_w,
    float* __restrict__ qkv) {
  int gid = blockIdx.x * 256 + threadIdx.x;   // 4*192*16384 total
  int pix = gid & (HWP - 1);
  int bc = gid >> 14;
  int ch = bc % 192;
  int y = pix >> 7, xx = pix & 127;
  const float* w = lce_w + ch * 9;
  const float* base = pre + (size_t)bc * HWP;
  float acc = 0.f;
#pragma unroll
  for (int dy = -1; dy <= 1; ++dy) {
    int yy = y + dy;
    if (yy < 0 || yy > 127) continue;
#pragma unroll
    for (int dx = -1; dx <= 1; ++dx) {
      int xc = xx + dx;
      if (xc < 0 || xc > 127) continue;
      acc = fmaf(w[(dy + 1) * 3 + dx + 1], base[yy * 128 + xc], acc);
    }
  }
  qkv[gid] = acc;
}

// ---------------- 3a: per-channel mean of q ----------------
__global__ __launch_bounds__(256) void k_mean(
    const float* __restrict__ qkv, float* __restrict__ mean) {
  int bc = blockIdx.x;              // b*64 + c
  int b = bc >> 6, c = bc & 63;
  const float* src = qkv + ((size_t)b * 192 + c) * HWP;
  float s = 0.f;
  for (int i = threadIdx.x; i < HWP; i += 256) s += src[i];
  __shared__ float red[4];
  for (int off = 32; off > 0; off >>= 1) s += __shfl_down(s, off);
  int t = threadIdx.x;
  if ((t & 63) == 0) red[t >> 6] = s;
  __syncthreads();
  if (t == 0) mean[bc] = (red[0] + red[1] + red[2] + red[3]) * (1.f / 16384.f);
}

// ---------------- 3b: centered cov partials (chunks of 128) ----------------
__global__ __launch_bounds__(256) void k_covpart(
    const float* __restrict__ qkv, const float* __restrict__ mean,
    float* __restrict__ covp) {
  int blk = blockIdx.x;             // b*128 + chunk
  int b = blk >> 7, chunk = blk & 127;
  int e0 = chunk * 128;
  __shared__ float qc[64 * 129];    // +1 pad breaks stride conflicts
  int t = threadIdx.x;
  for (int i = 0; i < 32; ++i) {
    int f = i * 256 + t;
    int c = f >> 7, e = f & 127;
    qc[c * 129 + e] = qkv[((size_t)b * 192 + c) * HWP + e0 + e] - mean[b * 64 + c];
  }
  __syncthreads();
  int d = t & 63;
  int crow = t >> 6;                // wave-uniform
  float acc[16];
#pragma unroll
  for (int i = 0; i < 16; ++i) acc[i] = 0.f;
  for (int e = 0; e < 128; ++e) {
    float qd = qc[d * 129 + e];
#pragma unroll
    for (int i = 0; i < 16; ++i) {
      int c = crow + 4 * i;
      acc[i] = fmaf(qc[c * 129 + e], qd, acc[i]);
    }
  }
  float* dst = covp + (size_t)blk * 4096;
#pragma unroll
  for (int i = 0; i < 16; ++i) {
    int c = crow + 4 * i;
    dst[c * 64 + d] = acc[i];       // == dst[i*256 + t], coalesced
  }
}

// ---------------- 3b2: reduce cov partials over 128 chunks (coalesced) ----------------
__global__ __launch_bounds__(256) void k_covred(
    const float* __restrict__ covp, float* __restrict__ covs) {
  int blk = blockIdx.x;             // b*16 + j
  int b = blk >> 4;
  int pp = (blk & 15) * 256 + threadIdx.x;
  const float* src = covp + (size_t)b * 524288 + pp;
  float s = 0.f;
  for (int ch = 0; ch < 128; ++ch) s += src[ch * 4096];   // chunk order preserved
  covs[b * 4096 + pp] = s;
}

// ---------------- 3c: correlation-mean sim, stable rank ----------------
__global__ __launch_bounds__(256) void k_simsort(
    const float* __restrict__ covs_g, int* __restrict__ idx, int* __restrict__ inv) {
  int b = blockIdx.x;               // 4 blocks
  __shared__ float covs[4096];
  __shared__ float stds[64];
  __shared__ float sims[64];
  int t = threadIdx.x;
  for (int i = 0; i < 16; ++i) covs[i * 256 + t] = covs_g[b * 4096 + i * 256 + t];
  __syncthreads();
  if (t < 64) stds[t] = sqrtf(covs[t * 64 + t] + 1e-8f);
  __syncthreads();
  if (t < 64) {
    float s = 0.f;
    float sc = stds[t];
    for (int d2 = 0; d2 < 64; ++d2) {
      float denom = fmaxf(sc * stds[d2], 1e-8f);
      s += covs[d2 * 64 + t] / denom;   // symmetric matrix: bitwise equal to [t][d2]
    }
    sims[t] = s * (1.f / 64.f);
  }
  __syncthreads();
  if (t < 64) {
    float sv = sims[t];
    int r = 0;
    for (int d2 = 0; d2 < 64; ++d2) {
      float o = sims[d2];
      if (o > sv || (o == sv && d2 < t)) r++;
    }
    idx[b * 64 + r] = t;
    inv[b * 64 + t] = r;
  }
}

// ---------------- 7: halo block attention + gate, scatter to original channels ----------------
__global__ __launch_bounds__(64) void k_attn(
    const float* __restrict__ qkv, const int* __restrict__ idx,
    const float* __restrict__ gate_w, const float* __restrict__ gate_b,
    const float* __restrict__ temp, const float* __restrict__ rel_h,
    const float* __restrict__ rel_w, float* __restrict__ attn_out) {
  int bi = blockIdx.x;
  int head = bi & 3;
  int wj = (bi >> 2) & 15;
  int hi = (bi >> 6) & 15;
  int b = bi >> 10;
  __shared__ __align__(16) float kr[100 * 20];  // stride 20: 80B rows, 16B aligned
  __shared__ __align__(16) float vr[100 * 20];
  __shared__ float rn[100];
  __shared__ float gw[256];
  __shared__ float gb[16];
  __shared__ int chg[16];
  int t = threadIdx.x;
  if (t < 16) {
    chg[t] = idx[b * 64 + head * 16 + t];
    gb[t] = gate_b[head * 16 + t];
  }
  __syncthreads();
  const size_t bb = (size_t)b * 192 * HWP;
  // K/V halo load, consecutive lanes -> consecutive positions (coalesced rows)
  for (int i = 0; i < 25; ++i) {
    int f = i * 64 + t;               // 1600 = 16ch * 100pos
    int ch = f / 100;
    int pos = f - ch * 100;
    int py = pos / 10, px = pos - py * 10;
    int ky = hi * 8 + py - 1, kx = wj * 8 + px - 1;
    bool ok = (ky >= 0) && (ky < 128) && (kx >= 0) && (kx < 128);
    int sp = ky * 128 + kx;
    float kv = ok ? qkv[bb + (size_t)(64 + chg[ch]) * HWP + sp] : 0.f;
    float vv = ok ? qkv[bb + (size_t)(128 + chg[ch]) * HWP + sp] : 0.f;
    kv += (ch < 8) ? rel_h[(head * 10 + py) * 8 + ch]
                   : rel_w[(head * 10 + px) * 8 + (ch - 8)];
    kr[pos * 20 + ch] = kv;
    vr[pos * 20 + ch] = vv;
  }
  for (int i = 0; i < 4; ++i) {
    int f = i * 64 + t;
    if (f < 256) gw[f] = gate_w[head * 256 + f];
  }
  __syncthreads();
  if (t < 100) {
    float s = 0.f;
#pragma unroll
    for (int ch = 0; ch < 16; ++ch) { float v = kr[t * 20 + ch]; s += v * v; }
    rn[t] = 1.f / fmaxf(sqrtf(s), 1e-12f);
  }
  { // remaining 36 rows
    int t2 = t + 64;
    if (t2 < 100) {
      float s = 0.f;
#pragma unroll
      for (int ch = 0; ch < 16; ++ch) { float v = kr[t2 * 20 + ch]; s += v * v; }
      rn[t2] = 1.f / fmaxf(sqrtf(s), 1e-12f);
    }
  }
  __syncthreads();
  // per-query
  int qy = hi * 8 + (t >> 3), qx = wj * 8 + (t & 7);
  float q[16];
  float qs = 0.f;
#pragma unroll
  for (int ch = 0; ch < 16; ++ch) {
    q[ch] = qkv[bb + (size_t)chg[ch] * HWP + qy * 128 + qx];
    qs += q[ch] * q[ch];
  }
  float qn = 1.f / fmaxf(sqrtf(qs), 1e-12f);
  float T = expf(temp[head]);
  float out[16];
#pragma unroll
  for (int ch = 0; ch < 16; ++ch) out[ch] = 0.f;
  float wsum = 0.f;
  for (int kk = 0; kk < 100; ++kk) {
    const float4* kp = (const float4*)(kr + kk * 20);
    const float4* vp = (const float4*)(vr + kk * 20);
    float kv[16], vv[16];
    *(float4*)(kv + 0)  = kp[0]; *(float4*)(kv + 4)  = kp[1];
    *(float4*)(kv + 8)  = kp[2]; *(float4*)(kv + 12) = kp[3];
    *(float4*)(vv + 0)  = vp[0]; *(float4*)(vv + 4)  = vp[1];
    *(float4*)(vv + 8)  = vp[2]; *(float4*)(vv + 12) = vp[3];
    float dacc = 0.f;
#pragma unroll
    for (int ch = 0; ch < 16; ++ch) dacc = fmaf(q[ch], kv[ch], dacc);
    float d = dacc * qn * rn[kk] * T;
    float e = expf(d - T);            // shift by upper bound: exact softmax, no max pass
    wsum += e;
#pragma unroll
    for (int ch = 0; ch < 16; ++ch) out[ch] = fmaf(e, vv[ch], out[ch]);
  }
  float winv = 1.f / wsum;
#pragma unroll
  for (int o = 0; o < 16; ++o) {
    float gsv = gb[o];
#pragma unroll
    for (int c = 0; c < 16; ++c) gsv = fmaf(gw[o * 16 + c], q[c], gsv);
    float sig = 1.f / (1.f + expf(-gsv));
    attn_out[((size_t)b * 64 + chg[o]) * HWP + qy * 128 + qx] = out[o] * winv * sig;
  }
}

// ---------------- 8: mixed -> gating -> down -> up -> (+attn) -> proj ----------------
// 1 wave per block, lane = pixel. xs is per-lane scratch [d][lane] (16 KB ->
// ~10 blocks/CU). Weights are d-major in global, read wave-uniform -> scalar
// s_load batches (16 KB/matrix fits scalar cache); acc[] in VGPRs, 64
// independent FMA chains. No barriers needed (single wave, lane-private cols).
__global__ __launch_bounds__(64) void k_post(
    const float* __restrict__ attn, const float* __restrict__ qkv,
    const float* __restrict__ gT, const float* __restrict__ gating_b,
    const float* __restrict__ dT, const float* __restrict__ down_b,
    const float* __restrict__ uT, const float* __restrict__ up_b,
    const float* __restrict__ pT, float* __restrict__ out3) {
  __shared__ float xs[64 * 64];     // [d][lane]
  int t = threadIdx.x;
  int p = blockIdx.x * 64 + t;      // global pooled pixel id
  int b = p >> 14;
  int pix = p & 16383;
  const float* ap = attn + (size_t)b * 64 * HWP + pix;
  const float* qp = qkv + (size_t)b * 192 * HWP + pix;
  float* op = out3 + (size_t)b * 64 * HWP + pix;
  // mixed = attn_out + (q + k)   (cache un-permutes to q+k)
  for (int c = 0; c < 64; ++c)
    xs[c * 64 + t] = ap[(size_t)c * HWP] + qp[(size_t)c * HWP] + qp[(size_t)(64 + c) * HWP];
  // ---- gating conv + exact gelu, * mixed ----
  {
    float acc[64];
#pragma unroll
    for (int o = 0; o < 64; ++o) acc[o] = gating_b[o];
    for (int d = 0; d < 64; ++d) {
      float xv = xs[d * 64 + t];
      const float* wd = gT + d * 64;          // wave-uniform -> s_load x16
#pragma unroll
      for (int o = 0; o < 64; ++o) acc[o] = fmaf(wd[o], xv, acc[o]);
    }
#pragma unroll
    for (int o = 0; o < 64; ++o) {
      float a = acc[o];
      float ge = 0.5f * a * (1.f + erff(a * 0.70710678118654752f));
      xs[o * 64 + t] = ge * xs[o * 64 + t];
    }
  }
  // ---- down 64->32 ----
  {
    float acc[32];
#pragma unroll
    for (int o = 0; o < 32; ++o) acc[o] = down_b[o];
    for (int d = 0; d < 64; ++d) {
      float xv = xs[d * 64 + t];
      const float* wd = dT + d * 32;
#pragma unroll
      for (int o = 0; o < 32; ++o) acc[o] = fmaf(wd[o], xv, acc[o]);
    }
#pragma unroll
    for (int o = 0; o < 32; ++o) xs[o * 64 + t] = acc[o];
  }
  // ---- up 32->64, + attn residual ----
  {
    float acc[64];
#pragma unroll
    for (int o = 0; o < 64; ++o) acc[o] = up_b[o];
    for (int d = 0; d < 32; ++d) {
      float xv = xs[d * 64 + t];
      const float* wd = uT + d * 64;
#pragma unroll
      for (int o = 0; o < 64; ++o) acc[o] = fmaf(wd[o], xv, acc[o]);
    }
#pragma unroll
    for (int o = 0; o < 64; ++o) xs[o * 64 + t] = acc[o] + ap[(size_t)o * HWP];
  }
  // ---- proj (no bias) ----
  {
    float acc[64];
#pragma unroll
    for (int o = 0; o < 64; ++o) acc[o] = 0.f;
    for (int d = 0; d < 64; ++d) {
      float xv = xs[d * 64 + t];
      const float* wd = pT + d * 64;
#pragma unroll
      for (int o = 0; o < 64; ++o) acc[o] = fmaf(wd[o], xv, acc[o]);
    }
#pragma unroll
    for (int o = 0; o < 64; ++o) op[(size_t)o * HWP] = acc[o];
  }
}

// ---------------- 9: dw3x3 reflect + bias + bilinear x2 (align-corners) ----------------
__global__ __launch_bounds__(256) void k_final(
    const float* __restrict__ out3, const float* __restrict__ lp_w,
    const float* __restrict__ lp_b, float* __restrict__ out) {
  int bi = blockIdx.x;                 // (b*64+ch)*8 + rt
  int rt = bi & 7;
  int bc = bi >> 3;
  int ch = bc & 63;
  int r0 = rt * 16;
  __shared__ float tin[20 * 128];      // input rows r0-2 .. r0+17 (reflected)
  __shared__ float tdw[18 * 128];      // dw rows r0-1 .. r0+16
  int t = threadIdx.x;
  const float* src = out3 + (size_t)bc * HWP;
  for (int i = 0; i < 10; ++i) {
    int f = i * 256 + t;               // 2560 exactly
    int r = f >> 7, xx = f & 127;
    int ry = r0 - 2 + r;
    ry = ry < 0 ? -ry : (ry > 127 ? 254 - ry : ry);
    tin[f] = src[ry * 128 + xx];
  }
  __syncthreads();
  float w0 = lp_w[ch * 9 + 0], w1 = lp_w[ch * 9 + 1], w2 = lp_w[ch * 9 + 2];
  float w3 = lp_w[ch * 9 + 3], w4 = lp_w[ch * 9 + 4], w5 = lp_w[ch * 9 + 5];
  float w6 = lp_w[ch * 9 + 6], w7 = lp_w[ch * 9 + 7], w8 = lp_w[ch * 9 + 8];
  float bias = lp_b[ch];
  for (int i = 0; i < 9; ++i) {
    int f = i * 256 + t;               // 2304 exactly
    int r = f >> 7, xx = f & 127;
    int xm = (xx == 0) ? 1 : xx - 1;
    int xp = (xx == 127) ? 126 : xx + 1;
    const float* r0p = tin + r * 128;
    const float* r1p = r0p + 128;
    const float* r2p = r1p + 128;
    float acc = bias;
    acc = fmaf(w0, r0p[xm], acc); acc = fmaf(w1, r0p[xx], acc); acc = fmaf(w2, r0p[xp], acc);
    acc = fmaf(w3, r1p[xm], acc); acc = fmaf(w4, r1p[xx], acc); acc = fmaf(w5, r1p[xp], acc);
    acc = fmaf(w6, r2p[xm], acc); acc = fmaf(w7, r2p[xx], acc); acc = fmaf(w8, r2p[xp], acc);
    tdw[f] = acc;
  }
  __syncthreads();
  const float s = (float)(127.0 / 255.0);
  float* dst = out + (size_t)bc * 65536;
  for (int i = 0; i < 32; ++i) {
    int f = i * 256 + t;               // 8192 exactly: rows 2r0..2r0+31, cols 0..255
    int vr = f >> 8, vx = f & 255;
    int v = 2 * r0 + vr;
    float cy = (float)v * s;
    int ly = (int)floorf(cy); if (ly > 126) ly = 126;
    float wy = cy - (float)ly;
    float cx = (float)vx * s;
    int lx = (int)floorf(cx); if (lx > 126) lx = 126;
    float wx = cx - (float)lx;
    int lr = ly - r0 + 1;              // tdw row index
    float a  = tdw[lr * 128 + lx];
    float bq = tdw[lr * 128 + lx + 1];
    float c2 = tdw[(lr + 1) * 128 + lx];
    float d2 = tdw[(lr + 1) * 128 + lx + 1];
    float t0 = a  * (1.f - wy) + c2 * wy;   // y-lerp first (matches ref order)
    float t1 = bq * (1.f - wy) + d2 * wy;
    dst[v * 256 + vx] = t0 * (1.f - wx) + t1 * wx;
  }
}

extern "C" void kernel_launch(void* const* d_in, const int* in_sizes, int n_in,
                              void* d_out, int out_size, void* d_ws, size_t ws_size,
                              hipStream_t stream) {
  (void)in_sizes; (void)n_in; (void)out_size; (void)ws_size;
  const float* x        = (const float*)d_in[0];
  const float* qkv_w    = (const float*)d_in[1];
  const float* lce_w    = (const float*)d_in[2];
  const float* gate_w   = (const float*)d_in[3];
  const float* gate_b   = (const float*)d_in[4];
  const float* temp     = (const float*)d_in[5];
  const float* rel_h    = (const float*)d_in[6];
  const float* rel_w    = (const float*)d_in[7];
  const float* down_w   = (const float*)d_in[8];
  const float* down_b   = (const float*)d_in[9];
  const float* up_w     = (const float*)d_in[10];
  const float* up_b     = (const float*)d_in[11];
  const float* gating_w = (const float*)d_in[12];
  const float* gating_b = (const float*)d_in[13];
  const float* proj_w   = (const float*)d_in[14];
  const float* lp_w     = (const float*)d_in[15];
  const float* lp_b     = (const float*)d_in[16];
  float* fws = (float*)d_ws;
  float* outp = (float*)d_out;

  float* pre  = fws + PRE_OFF;
  float* qkv  = fws + QKV_OFF;
  float* attn = fws + ATTN_OFF;
  float* out3 = fws + OUT3_OFF;
  float* covp = fws + COVP_OFF;
  float* mean = fws + MEAN_OFF;
  int* idx = (int*)(fws + IDX_OFF);
  int* inv = (int*)(fws + INV_OFF);
  float* covs = fws + COVS_OFF;
  float* wT   = fws + WT_OFF;
  float* gT   = fws + GT2_OFF;
  float* dT   = fws + DT2_OFF;
  float* uT   = fws + UT2_OFF;
  float* pT   = fws + PT2_OFF;

  k_prep_wt<<<48, 256, 0, stream>>>(qkv_w, wT);
  k_pool_conv<<<1024, 256, 0, stream>>>(x, wT, pre);
  k_dw3x3_zero<<<49152, 256, 0, stream>>>(pre, lce_w, qkv);
  k_prep2<<<16, 256, 0, stream>>>(gating_w, down_w, up_w, proj_w, gT, dT, uT, pT);
  k_mean<<<256, 256, 0, stream>>>(qkv, mean);
  k_covpart<<<512, 256, 0, stream>>>(qkv, mean, covp);
  k_covred<<<64, 256, 0, stream>>>(covp, covs);
  k_simsort<<<4, 256, 0, stream>>>(covs, idx, inv);
  k_attn<<<4096, 64, 0, stream>>>(qkv, idx, gate_w, gate_b, temp, rel_h, rel_w, attn);
  k_post<<<1024, 64, 0, stream>>>(attn, qkv, gT, gating_b, dT, down_b,
                                  uT, up_b, pT, out3);
  k_final<<<2048, 256, 0, stream>>>(out3, lp_w, lp_b, outp);
  (void)inv;
}